// Round 9
// baseline (206.924 us; speedup 1.0000x reference)
//
#include <hip/hip_runtime.h>
#include <hip/hip_bf16.h>

// ContralateralAttention, round 21: proj -> M=32/BK=32, 256thr, grid 1024, 34KB LDS
// = 4 independent blocks/CU. Evidence across r1/r13/r16-r20: proj time tracks blocks/CU
// (1/CU: 47-60us; 2/CU: 40.5us), not schedule shape — barrier drains are per-block and
// co-resident independent blocks hide them. Same r1 2-barrier schedule + proven swizzles.
// prep/gemm/attn unchanged from r17/r5 (validated best total 180.8).
// ws layout (MB): Xbf [0,16) | wbf [16,17) | qkv [17,65) | ctx [65,81)

#define NTOK 32768

using bf16x8 = __attribute__((ext_vector_type(8))) short;
using f32x4  = __attribute__((ext_vector_type(4))) float;

__device__ __forceinline__ float b2f(short s) {
    unsigned u = ((unsigned)(unsigned short)s) << 16;
    union { unsigned u; float f; } c; c.u = u; return c.f;
}
__device__ __forceinline__ short f2b(float f) {
    __hip_bfloat16 h = __float2bfloat16(f);
    return *(short*)&h;
}
__device__ __forceinline__ void async_copy16(const void* g, void* l) {
    __builtin_amdgcn_global_load_lds(
        (const __attribute__((address_space(1))) unsigned int*)g,
        (__attribute__((address_space(3))) unsigned int*)l, 16, 0, 0);
}

// ---------------- prep: vectorized feat transpose+cast AND weight casts ----------------
__global__ __launch_bounds__(256) void prep_kernel(const float* __restrict__ feat,
                                                   const float* __restrict__ in_w,
                                                   const float* __restrict__ out_w,
                                                   const float* __restrict__ proj_w,
                                                   __hip_bfloat16* __restrict__ X,
                                                   __hip_bfloat16* __restrict__ wbf) {
    const int bid = blockIdx.x;
    const int tid = threadIdx.x;
    if (bid < 4096) {
        __shared__ float tile[32][68];
        const int b   = bid >> 9;
        const int rem = bid & 511;
        const int sp0 = (rem & 63) * 64;
        const int c0  = (rem >> 6) * 32;
        #pragma unroll
        for (int u = 0; u < 2; ++u) {
            const int idx = tid + u * 256;      // 0..511
            const int cl = idx >> 4;            // 0..31
            const int sq = (idx & 15) * 4;      // 0..60
            const float4 v = *(const float4*)(feat + ((size_t)(b * 256 + c0 + cl) << 12) + sp0 + sq);
            tile[cl][sq]     = v.x;
            tile[cl][sq + 1] = v.y;
            tile[cl][sq + 2] = v.z;
            tile[cl][sq + 3] = v.w;
        }
        __syncthreads();
        #pragma unroll
        for (int u = 0; u < 2; ++u) {
            const int idx = tid + u * 256;      // 0..511
            const int tok = idx >> 3;           // 0..63
            const int cq  = (idx & 7) * 4;      // 0..28
            short4 s;
            s.x = f2b(tile[cq][tok]);
            s.y = f2b(tile[cq + 1][tok]);
            s.z = f2b(tile[cq + 2][tok]);
            s.w = f2b(tile[cq + 3][tok]);
            *(short4*)(X + (size_t)(b * 4096 + sp0 + tok) * 256 + c0 + cq) = s;
        }
    } else {
        const int i4 = (bid - 4096) * 1024 + tid * 4;
        if (i4 < 196608) {
            const float4 v = *(const float4*)(in_w + i4);
            short4 s = {f2b(v.x), f2b(v.y), f2b(v.z), f2b(v.w)};
            *(short4*)(wbf + i4) = s;
        }
        if (i4 < 65536) {
            const float4 v = *(const float4*)(out_w + i4);
            short4 s = {f2b(v.x), f2b(v.y), f2b(v.z), f2b(v.w)};
            *(short4*)(wbf + 196608 + i4) = s;
        }
        if (i4 < 262144) {
            const float4 v = *(const float4*)(proj_w + i4);
            short4 s = {f2b(v.x), f2b(v.y), f2b(v.z), f2b(v.w)};
            *(short4*)(wbf + 262144 + i4) = s;
        }
    }
}

// ---------------- MFMA GEMM (qkv): 256 thr, M=128 x N=128, BK=64, 2-phase dbuf ----------------
// 1D grid 1536, XCD-chunked work order: work=(bid&7)*192+(bid>>3); xb=work/6 (A-tile), yb=work%6.
template <int KDIM, bool OUT_BF16>
__global__ __launch_bounds__(256) void mfma_gemm(const __hip_bfloat16* __restrict__ A,
                                                 const __hip_bfloat16* __restrict__ W,
                                                 const float* __restrict__ bias,
                                                 void* __restrict__ C, int Ntot) {
    __shared__ __align__(16) short As[2][128 * 64];   // 2 x 16 KB
    __shared__ __align__(16) short Bs[2][128 * 64];   // 2 x 16 KB
    const int tid = threadIdx.x;
    const int work = (blockIdx.x & 7) * 192 + (blockIdx.x >> 3);
    const int m0 = (work / 6) * 128;
    const int n0 = (work % 6) * 128;
    const int wave = tid >> 6, lane = tid & 63;
    const int wm = (wave >> 1) * 64;
    const int wn = (wave & 1) * 64;
    const int fm = lane & 15;
    const int fq = lane >> 4;

    // prologue: stage K-slice 0 into buffer 0
    #pragma unroll
    for (int v = 0; v < 4; ++v) {
        const int qb = v * 256 + wave * 64;
        const int q = qb + lane;
        const int r = q >> 3;
        const int cs = (q & 7) ^ (r & 7);
        async_copy16(A + (size_t)(m0 + r) * KDIM + cs * 8, &As[0][qb * 8]);
        async_copy16(W + (size_t)(n0 + r) * KDIM + cs * 8, &Bs[0][qb * 8]);
    }
    __syncthreads();

    f32x4 acc[4][4] = {};
    #pragma unroll
    for (int t = 0; t < KDIM / 64; ++t) {
        const int cur = t & 1;
        if (t + 1 < KDIM / 64) {                       // issue next-slice stage FIRST
            #pragma unroll
            for (int v = 0; v < 4; ++v) {
                const int qb = v * 256 + wave * 64;
                const int q = qb + lane;
                const int r = q >> 3;
                const int cs = (q & 7) ^ (r & 7);
                async_copy16(A + (size_t)(m0 + r) * KDIM + (t + 1) * 64 + cs * 8, &As[cur ^ 1][qb * 8]);
                async_copy16(W + (size_t)(n0 + r) * KDIM + (t + 1) * 64 + cs * 8, &Bs[cur ^ 1][qb * 8]);
            }
        }
        #pragma unroll
        for (int kk = 0; kk < 2; ++kk) {
            bf16x8 af[4], bw[4];
            #pragma unroll
            for (int i = 0; i < 4; ++i) {
                const int row = wm + i * 16 + fm;
                af[i] = *(const bf16x8*)(&As[cur][row * 64 + (((fq + kk * 4) ^ (fm & 7)) * 8)]);
            }
            #pragma unroll
            for (int j = 0; j < 4; ++j) {
                const int row = wn + j * 16 + fm;
                bw[j] = *(const bf16x8*)(&Bs[cur][row * 64 + (((fq + kk * 4) ^ (fm & 7)) * 8)]);
            }
            #pragma unroll
            for (int i = 0; i < 4; ++i)
                #pragma unroll
                for (int j = 0; j < 4; ++j)
                    acc[i][j] = __builtin_amdgcn_mfma_f32_16x16x32_bf16(af[i], bw[j], acc[i][j], 0, 0, 0);
        }
        __syncthreads();                               // one barrier per K-step
    }
    #pragma unroll
    for (int j = 0; j < 4; ++j) {
        const int col = n0 + wn + j * 16 + fm;
        const float bv = bias[col];
        #pragma unroll
        for (int i = 0; i < 4; ++i) {
            #pragma unroll
            for (int r = 0; r < 4; ++r) {
                const int row = m0 + wm + i * 16 + fq * 4 + r;
                const float v = acc[i][j][r] + bv;
                if (OUT_BF16)
                    ((__hip_bfloat16*)C)[(size_t)row * Ntot + col] = __float2bfloat16(v);
                else
                    ((float*)C)[(size_t)row * Ntot + col] = v;
            }
        }
    }
}

// ---------------- sparse attention (r7 form, validated) ----------------
#define P0DY ((2u)|(2u<<3)|(2u<<6)|(2u<<9)|(2u<<12)|(1u<<15)|(1u<<18)|(1u<<21))
#define P0DX ((2u)|(1u<<3)|(3u<<6)|(0u<<9)|(4u<<12)|(2u<<15)|(1u<<18)|(3u<<21))
#define P1DY ((3u)|(3u<<3)|(3u<<6)|(0u<<9)|(4u<<12)|(2u<<15)|(2u<<18)|(2u<<21))
#define P1DX ((2u)|(1u<<3)|(3u<<6)|(2u<<9)|(2u<<12)|(2u<<15)|(2u<<18)|(2u<<21))

__global__ __launch_bounds__(256) void attn_kernel(const __hip_bfloat16* __restrict__ qkv,
                                                   __hip_bfloat16* __restrict__ ctx) {
    const int t = blockIdx.x * 4 + (threadIdx.x >> 6);
    const int lane = threadIdx.x & 63;
    const int n  = lane >> 3;
    const int cg = lane & 7;
    const int x6 = t & 63;
    const int yq = (t >> 6) & 63;
    const int b  = t >> 12;
    const int side = x6 >> 5;
    const int x = x6 & 31;

    bool valid[2];
    size_t kb[2];
    #pragma unroll
    for (int p = 0; p < 2; ++p) {
        const unsigned dyp = p ? P1DY : P0DY;
        const unsigned dxp = p ? P1DX : P0DX;
        const int sh = 3 * n;
        const int dy = (int)((dyp >> sh) & 7) - 2;
        const int dx = (int)((dxp >> sh) & 7) - 2;
        const int yy = yq + dy, xx = x + dx;
        valid[p] = (p == 0 || n < 5) && yy >= 0 && yy < 64 && xx >= 0 && xx < 32;
        const int xm = side ? (31 - xx) : (63 - xx);
        int tm = (b << 12) + (yy << 6) + xm;
        if (!valid[p]) tm = t;
        kb[p] = (size_t)tm * 768 + 256 + cg * 8;
    }
    const size_t qb = (size_t)t * 768 + cg * 8;
    const size_t ob = (size_t)t * 256;

    #pragma unroll
    for (int hp = 0; hp < 2; ++hp) {
        bf16x8 q8[2], k8[2][2], v8[2][2];
        #pragma unroll
        for (int hh = 0; hh < 2; ++hh) {
            const int h = hp * 2 + hh;
            q8[hh] = *(const bf16x8*)(qkv + qb + h * 64);
            #pragma unroll
            for (int p = 0; p < 2; ++p) {
                k8[hh][p] = *(const bf16x8*)(qkv + kb[p] + h * 64);
                v8[hh][p] = *(const bf16x8*)(qkv + kb[p] + h * 64 + 256);
            }
        }
        #pragma unroll
        for (int hh = 0; hh < 2; ++hh) {
            float sc[2];
            #pragma unroll
            for (int p = 0; p < 2; ++p) {
                float s = 0.f;
                #pragma unroll
                for (int j = 0; j < 8; ++j) s += b2f(q8[hh][j]) * b2f(k8[hh][p][j]);
                s += __shfl_xor(s, 1, 64);
                s += __shfl_xor(s, 2, 64);
                s += __shfl_xor(s, 4, 64);
                sc[p] = valid[p] ? s * 0.125f : -1e30f;
            }
            const float p0 = __expf(sc[0]);
            const float p1 = __expf(sc[1]);
            float l = p0 + p1;
            l += __shfl_xor(l, 8, 64);
            l += __shfl_xor(l, 16, 64);
            l += __shfl_xor(l, 32, 64);

            float o[8];
            #pragma unroll
            for (int j = 0; j < 8; ++j)
                o[j] = p0 * b2f(v8[hh][0][j]) + p1 * b2f(v8[hh][1][j]);
            float r4[4];
            #pragma unroll
            for (int i = 0; i < 4; ++i) {
                const float a = o[2 * i], bb = o[2 * i + 1];
                const float mine = (n & 1) ? bb : a;
                const float theirs = (n & 1) ? a : bb;
                r4[i] = mine + __shfl_xor(theirs, 8, 64);
            }
            float r2[2];
            #pragma unroll
            for (int i = 0; i < 2; ++i) {
                const float a = r4[2 * i], bb = r4[2 * i + 1];
                const float mine = (n & 2) ? bb : a;
                const float theirs = (n & 2) ? a : bb;
                r2[i] = mine + __shfl_xor(theirs, 16, 64);
            }
            float ov;
            {
                const float a = r2[0], bb = r2[1];
                const float mine = (n & 4) ? bb : a;
                const float theirs = (n & 4) ? a : bb;
                ov = mine + __shfl_xor(theirs, 32, 64);
            }
            const float rl = __builtin_amdgcn_rcpf(l);
            ctx[ob + (hp * 2 + hh) * 64 + cg * 8 + n] = __float2bfloat16(ov * rl);
        }
    }
}

// ---------------- fused: ctx2 = ctx@out_w^T+out_b (in LDS), then proj+LN+ReLU+store ----------------
// r21: M=32, BK=32, 256 thr / 4 waves (1M x 4N), grid 1024, LDS 34KB -> 4 blocks/CU.
// Same r1 2-barrier schedule; r19's BK=32 stage/read swizzle; r1's c2s slot swizzle.
__global__ __launch_bounds__(256) void proj_ln_fused(const __hip_bfloat16* __restrict__ X,
                                                     const __hip_bfloat16* __restrict__ CTX,
                                                     const __hip_bfloat16* __restrict__ W2,
                                                     const float* __restrict__ out_b,
                                                     const __hip_bfloat16* __restrict__ W,
                                                     const float* __restrict__ bias,
                                                     const float* __restrict__ ln_g,
                                                     const float* __restrict__ ln_b,
                                                     float* __restrict__ out) {
    __shared__ __align__(16) short smem[17408];   // 34 KB
    __shared__ float mu_s[32], inv_s[32];
    short* c2s = smem;              // 32 x 256 (16 KB), persists through phase B
    short* As  = smem + 8192;       // 32 x 32 (2 KB) staging
    short* Bs  = smem + 9216;       // 256 x 32 (16 KB) staging
    const int tid = threadIdx.x;
    const int m0 = blockIdx.x * 32;
    const int b = m0 >> 12, sp0 = m0 & 4095;
    const int wave = tid >> 6, lane = tid & 63;
    const int wn = wave * 64;           // N-quarter
    const int fm = lane & 15;
    const int fq = lane >> 4;

    // BK=32 staging: As 128 chunks (tid<128, 1 each), Bs 1024 chunks (4 each).
    // swizzle: slot (q&3) holds global chunk (q&3)^((r>>1)&3); read slot fq^((row>>1)&3).
    auto stageA = [&](const __hip_bfloat16* src, int k0) {
        if (wave < 2) {
            const int r = tid >> 2;               // 0..31
            const int cs = (tid & 3) ^ ((r >> 1) & 3);
            async_copy16(src + (size_t)(m0 + r) * 256 + k0 + cs * 8, &As[(wave * 64) * 8]);
        }
    };
    auto stageB = [&](const __hip_bfloat16* src, int ldk, int k0) {
        #pragma unroll
        for (int v = 0; v < 4; ++v) {
            const int q = v * 256 + tid;          // 0..1023, row = q>>2
            const int r = q >> 2;
            const int cs = (q & 3) ^ ((r >> 1) & 3);
            async_copy16(src + (size_t)r * ldk + k0 + cs * 8, &Bs[(v * 256 + wave * 64) * 8]);
        }
    };

    // ---- phase A: ctx2 = ctx @ out_w^T, K=256 in 8 BK=32 steps ----
    f32x4 acc2[2][4] = {};
    for (int t = 0; t < 8; ++t) {
        stageA(CTX, t * 32);
        stageB(W2, 256, t * 32);
        __syncthreads();
        bf16x8 af[2], bw[4];
        #pragma unroll
        for (int i = 0; i < 2; ++i) {
            const int row = i * 16 + fm;
            af[i] = *(const bf16x8*)(&As[row * 32 + ((fq ^ ((row >> 1) & 3)) * 8)]);
        }
        #pragma unroll
        for (int j = 0; j < 4; ++j) {
            const int row = wn + j * 16 + fm;
            bw[j] = *(const bf16x8*)(&Bs[row * 32 + ((fq ^ ((row >> 1) & 3)) * 8)]);
        }
        #pragma unroll
        for (int i = 0; i < 2; ++i)
            #pragma unroll
            for (int j = 0; j < 4; ++j)
                acc2[i][j] = __builtin_amdgcn_mfma_f32_16x16x32_bf16(af[i], bw[j], acc2[i][j], 0, 0, 0);
        __syncthreads();
    }
    // write c2 tile (bias added), r1 slot swizzle
    #pragma unroll
    for (int j = 0; j < 4; ++j) {
        const int col = wn + j * 16 + fm;
        const float bv = out_b[col];
        const int jch = col >> 3, cl = col & 7;
        #pragma unroll
        for (int i = 0; i < 2; ++i)
            #pragma unroll
            for (int rr = 0; rr < 4; ++rr) {
                const int row = i * 16 + fq * 4 + rr;
                const int slot = (jch & 24) | ((jch & 7) ^ (row & 7));
                c2s[row * 256 + slot * 8 + cl] = f2b(acc2[i][j][rr] + bv);
            }
    }
    __syncthreads();

    // ---- phase B: proj over K=1024 = [q | c2 | |q-c2| | q*c2], 32 BK=32 steps ----
    f32x4 acc[2][4] = {};
    for (int s = 0; s < 32; ++s) {
        const int g = s >> 3;
        const int cb = (s & 7) * 32;              // col offset within 256
        stageB(W, 1024, s * 32);
        if (g == 0) {
            stageA(X, cb);
        } else if (g >= 2) {
            if (wave < 2) {                        // build |q-c2| / q*c2 into As
                const int r = tid >> 2;
                const int cs = (tid & 3) ^ ((r >> 1) & 3);
                int4 qraw = *(const int4*)(X + (size_t)(m0 + r) * 256 + cb + cs * 8);
                const int jch = (cb >> 3) + cs;
                const int slot = (jch & 24) | ((jch & 7) ^ (r & 7));
                int4 craw = *(const int4*)(&c2s[r * 256 + slot * 8]);
                const short* qs = (const short*)&qraw;
                const short* cw = (const short*)&craw;
                short tmp[8];
                #pragma unroll
                for (int j = 0; j < 8; ++j) {
                    const float qv = b2f(qs[j]), cv = b2f(cw[j]);
                    tmp[j] = f2b(g == 2 ? fabsf(qv - cv) : qv * cv);
                }
                *(int4*)(&As[tid * 8]) = *(int4*)tmp;
            }
        }
        // g == 1: no A staging — frags read straight from c2s
        __syncthreads();
        bf16x8 af[2], bw[4];
        if (g == 1) {
            #pragma unroll
            for (int i = 0; i < 2; ++i) {
                const int row = i * 16 + fm;
                const int jch = (cb >> 3) + fq;
                const int slot = (jch & 24) | ((jch & 7) ^ (row & 7));
                af[i] = *(const bf16x8*)(&c2s[row * 256 + slot * 8]);
            }
        } else {
            #pragma unroll
            for (int i = 0; i < 2; ++i) {
                const int row = i * 16 + fm;
                af[i] = *(const bf16x8*)(&As[row * 32 + ((fq ^ ((row >> 1) & 3)) * 8)]);
            }
        }
        #pragma unroll
        for (int j = 0; j < 4; ++j) {
            const int row = wn + j * 16 + fm;
            bw[j] = *(const bf16x8*)(&Bs[row * 32 + ((fq ^ ((row >> 1) & 3)) * 8)]);
        }
        #pragma unroll
        for (int i = 0; i < 2; ++i)
            #pragma unroll
            for (int j = 0; j < 4; ++j)
                acc[i][j] = __builtin_amdgcn_mfma_f32_16x16x32_bf16(af[i], bw[j], acc[i][j], 0, 0, 0);
        __syncthreads();
    }

    // ---- epilogue: ys (bf16, stride 266) overlays smem (dead); LN; ReLU; store ----
    short* ys = smem;
    #pragma unroll
    for (int j = 0; j < 4; ++j) {
        const int col = wn + j * 16 + fm;
        const float bv = bias[col];
        #pragma unroll
        for (int i = 0; i < 2; ++i)
            #pragma unroll
            for (int r = 0; r < 4; ++r)
                ys[(i * 16 + fq * 4 + r) * 266 + col] = f2b(acc[i][j][r] + bv);
    }
    __syncthreads();
    {
        const int tt = tid >> 3, seg = tid & 7;   // 32 rows x 8 segs of 32
        float s = 0.f, ss = 0.f;
        #pragma unroll
        for (int j = 0; j < 32; ++j) {
            const float v = b2f(ys[tt * 266 + seg * 32 + j]);
            s += v; ss += v * v;
        }
        s += __shfl_xor(s, 1, 64);  ss += __shfl_xor(ss, 1, 64);
        s += __shfl_xor(s, 2, 64);  ss += __shfl_xor(ss, 2, 64);
        s += __shfl_xor(s, 4, 64);  ss += __shfl_xor(ss, 4, 64);
        if (seg == 0) {
            const float mu = s * (1.f / 256.f);
            const float var = ss * (1.f / 256.f) - mu * mu;
            mu_s[tt] = mu;
            inv_s[tt] = rsqrtf(var + 1e-5f);
        }
    }
    __syncthreads();
    {
        const int tl = tid & 31;                  // row 0..31
        const int j0 = tid >> 5;                  // 8 col-blocks of 32
        const float mu = mu_s[tl], inv = inv_s[tl];
        #pragma unroll
        for (int u = 0; u < 32; ++u) {
            const int j = j0 * 32 + u;
            const float v = (b2f(ys[tl * 266 + j]) - mu) * inv * ln_g[j] + ln_b[j];
            out[((size_t)(b * 256 + j) << 12) + sp0 + tl] = fmaxf(v, 0.f);
        }
    }
}

extern "C" void kernel_launch(void* const* d_in, const int* in_sizes, int n_in,
                              void* d_out, int out_size, void* d_ws, size_t ws_size,
                              hipStream_t stream) {
    (void)in_sizes; (void)n_in; (void)out_size; (void)ws_size;
    const float* feat   = (const float*)d_in[0];
    const float* in_w   = (const float*)d_in[1];
    const float* in_b   = (const float*)d_in[2];
    const float* out_w  = (const float*)d_in[3];
    const float* out_b  = (const float*)d_in[4];
    const float* proj_w = (const float*)d_in[5];
    const float* proj_b = (const float*)d_in[6];
    const float* ln_g   = (const float*)d_in[7];
    const float* ln_b   = (const float*)d_in[8];
    float* out = (float*)d_out;

    char* ws = (char*)d_ws;
    __hip_bfloat16* Xbf  = (__hip_bfloat16*)(ws);
    __hip_bfloat16* wbf  = (__hip_bfloat16*)(ws + (size_t)(16) * (1 << 20));
    __hip_bfloat16* qkv  = (__hip_bfloat16*)(ws + (size_t)(17) * (1 << 20));
    __hip_bfloat16* ctx  = (__hip_bfloat16*)(ws + (size_t)(65) * (1 << 20));
    __hip_bfloat16* in_wbf   = wbf;
    __hip_bfloat16* out_wbf  = wbf + 196608;
    __hip_bfloat16* proj_wbf = wbf + 262144;

    prep_kernel   <<<4352, 256, 0, stream>>>(feat, in_w, out_w, proj_w, Xbf, wbf);
    mfma_gemm<256, true><<<1536, 256, 0, stream>>>(Xbf, in_wbf, in_b, qkv, 768);
    attn_kernel   <<<NTOK / 4, 256, 0, stream>>>(qkv, ctx);
    proj_ln_fused <<<NTOK / 32, 256, 0, stream>>>(Xbf, ctx, out_wbf, out_b,
                                                  proj_wbf, proj_b, ln_g, ln_b, out);
}

// Round 10
// 202.470 us; speedup vs baseline: 1.0220x; 1.0220x over previous
//
#include <hip/hip_runtime.h>
#include <hip/hip_bf16.h>

// ContralateralAttention, round 22: attn rewritten as 2D-tiled LDS kernel.
// Old attn: wave-per-token, 16KB scattered K/V gathers/token -> ~512MB through L2/L3 (~11x
// amplification, qkv 48MB > 32MB L2). New: block = 4x4 token tile; neighbor union = 8x8
// positions; stage K+V (64KB LDS, XOR-swizzle, edge-clamped; clamps masked by valid->exp(-1e30))
// once, then 4 waves x 4 tokens compute from LDS. Math identical to validated r7 form.
// proj reverted to r1/r17 form (40.5us local optimum; M=128/1blk=46.6, M=32/4blk=69 both worse).
// prep/gemm unchanged (r5 validated, total 180.8).
// ws layout (MB): Xbf [0,16) | wbf [16,17) | qkv [17,65) | ctx [65,81)

#define NTOK 32768

using bf16x8 = __attribute__((ext_vector_type(8))) short;
using f32x4  = __attribute__((ext_vector_type(4))) float;

__device__ __forceinline__ float b2f(short s) {
    unsigned u = ((unsigned)(unsigned short)s) << 16;
    union { unsigned u; float f; } c; c.u = u; return c.f;
}
__device__ __forceinline__ short f2b(float f) {
    __hip_bfloat16 h = __float2bfloat16(f);
    return *(short*)&h;
}
__device__ __forceinline__ void async_copy16(const void* g, void* l) {
    __builtin_amdgcn_global_load_lds(
        (const __attribute__((address_space(1))) unsigned int*)g,
        (__attribute__((address_space(3))) unsigned int*)l, 16, 0, 0);
}

// ---------------- prep: vectorized feat transpose+cast AND weight casts ----------------
__global__ __launch_bounds__(256) void prep_kernel(const float* __restrict__ feat,
                                                   const float* __restrict__ in_w,
                                                   const float* __restrict__ out_w,
                                                   const float* __restrict__ proj_w,
                                                   __hip_bfloat16* __restrict__ X,
                                                   __hip_bfloat16* __restrict__ wbf) {
    const int bid = blockIdx.x;
    const int tid = threadIdx.x;
    if (bid < 4096) {
        __shared__ float tile[32][68];
        const int b   = bid >> 9;
        const int rem = bid & 511;
        const int sp0 = (rem & 63) * 64;
        const int c0  = (rem >> 6) * 32;
        #pragma unroll
        for (int u = 0; u < 2; ++u) {
            const int idx = tid + u * 256;      // 0..511
            const int cl = idx >> 4;            // 0..31
            const int sq = (idx & 15) * 4;      // 0..60
            const float4 v = *(const float4*)(feat + ((size_t)(b * 256 + c0 + cl) << 12) + sp0 + sq);
            tile[cl][sq]     = v.x;
            tile[cl][sq + 1] = v.y;
            tile[cl][sq + 2] = v.z;
            tile[cl][sq + 3] = v.w;
        }
        __syncthreads();
        #pragma unroll
        for (int u = 0; u < 2; ++u) {
            const int idx = tid + u * 256;      // 0..511
            const int tok = idx >> 3;           // 0..63
            const int cq  = (idx & 7) * 4;      // 0..28
            short4 s;
            s.x = f2b(tile[cq][tok]);
            s.y = f2b(tile[cq + 1][tok]);
            s.z = f2b(tile[cq + 2][tok]);
            s.w = f2b(tile[cq + 3][tok]);
            *(short4*)(X + (size_t)(b * 4096 + sp0 + tok) * 256 + c0 + cq) = s;
        }
    } else {
        const int i4 = (bid - 4096) * 1024 + tid * 4;
        if (i4 < 196608) {
            const float4 v = *(const float4*)(in_w + i4);
            short4 s = {f2b(v.x), f2b(v.y), f2b(v.z), f2b(v.w)};
            *(short4*)(wbf + i4) = s;
        }
        if (i4 < 65536) {
            const float4 v = *(const float4*)(out_w + i4);
            short4 s = {f2b(v.x), f2b(v.y), f2b(v.z), f2b(v.w)};
            *(short4*)(wbf + 196608 + i4) = s;
        }
        if (i4 < 262144) {
            const float4 v = *(const float4*)(proj_w + i4);
            short4 s = {f2b(v.x), f2b(v.y), f2b(v.z), f2b(v.w)};
            *(short4*)(wbf + 262144 + i4) = s;
        }
    }
}

// ---------------- MFMA GEMM (qkv): 256 thr, M=128 x N=128, BK=64, 2-phase dbuf ----------------
template <int KDIM, bool OUT_BF16>
__global__ __launch_bounds__(256) void mfma_gemm(const __hip_bfloat16* __restrict__ A,
                                                 const __hip_bfloat16* __restrict__ W,
                                                 const float* __restrict__ bias,
                                                 void* __restrict__ C, int Ntot) {
    __shared__ __align__(16) short As[2][128 * 64];   // 2 x 16 KB
    __shared__ __align__(16) short Bs[2][128 * 64];   // 2 x 16 KB
    const int tid = threadIdx.x;
    const int work = (blockIdx.x & 7) * 192 + (blockIdx.x >> 3);
    const int m0 = (work / 6) * 128;
    const int n0 = (work % 6) * 128;
    const int wave = tid >> 6, lane = tid & 63;
    const int wm = (wave >> 1) * 64;
    const int wn = (wave & 1) * 64;
    const int fm = lane & 15;
    const int fq = lane >> 4;

    #pragma unroll
    for (int v = 0; v < 4; ++v) {
        const int qb = v * 256 + wave * 64;
        const int q = qb + lane;
        const int r = q >> 3;
        const int cs = (q & 7) ^ (r & 7);
        async_copy16(A + (size_t)(m0 + r) * KDIM + cs * 8, &As[0][qb * 8]);
        async_copy16(W + (size_t)(n0 + r) * KDIM + cs * 8, &Bs[0][qb * 8]);
    }
    __syncthreads();

    f32x4 acc[4][4] = {};
    #pragma unroll
    for (int t = 0; t < KDIM / 64; ++t) {
        const int cur = t & 1;
        if (t + 1 < KDIM / 64) {
            #pragma unroll
            for (int v = 0; v < 4; ++v) {
                const int qb = v * 256 + wave * 64;
                const int q = qb + lane;
                const int r = q >> 3;
                const int cs = (q & 7) ^ (r & 7);
                async_copy16(A + (size_t)(m0 + r) * KDIM + (t + 1) * 64 + cs * 8, &As[cur ^ 1][qb * 8]);
                async_copy16(W + (size_t)(n0 + r) * KDIM + (t + 1) * 64 + cs * 8, &Bs[cur ^ 1][qb * 8]);
            }
        }
        #pragma unroll
        for (int kk = 0; kk < 2; ++kk) {
            bf16x8 af[4], bw[4];
            #pragma unroll
            for (int i = 0; i < 4; ++i) {
                const int row = wm + i * 16 + fm;
                af[i] = *(const bf16x8*)(&As[cur][row * 64 + (((fq + kk * 4) ^ (fm & 7)) * 8)]);
            }
            #pragma unroll
            for (int j = 0; j < 4; ++j) {
                const int row = wn + j * 16 + fm;
                bw[j] = *(const bf16x8*)(&Bs[cur][row * 64 + (((fq + kk * 4) ^ (fm & 7)) * 8)]);
            }
            #pragma unroll
            for (int i = 0; i < 4; ++i)
                #pragma unroll
                for (int j = 0; j < 4; ++j)
                    acc[i][j] = __builtin_amdgcn_mfma_f32_16x16x32_bf16(af[i], bw[j], acc[i][j], 0, 0, 0);
        }
        __syncthreads();
    }
    #pragma unroll
    for (int j = 0; j < 4; ++j) {
        const int col = n0 + wn + j * 16 + fm;
        const float bv = bias[col];
        #pragma unroll
        for (int i = 0; i < 4; ++i) {
            #pragma unroll
            for (int r = 0; r < 4; ++r) {
                const int row = m0 + wm + i * 16 + fq * 4 + r;
                const float v = acc[i][j][r] + bv;
                if (OUT_BF16)
                    ((__hip_bfloat16*)C)[(size_t)row * Ntot + col] = __float2bfloat16(v);
                else
                    ((float*)C)[(size_t)row * Ntot + col] = v;
            }
        }
    }
}

// ---------------- tiled sparse attention: block = 4x4 tokens, K/V box 8x8 in LDS ----------------
#define P0DY ((2u)|(2u<<3)|(2u<<6)|(2u<<9)|(2u<<12)|(1u<<15)|(1u<<18)|(1u<<21))
#define P0DX ((2u)|(1u<<3)|(3u<<6)|(0u<<9)|(4u<<12)|(2u<<15)|(1u<<18)|(3u<<21))
#define P1DY ((3u)|(3u<<3)|(3u<<6)|(0u<<9)|(4u<<12)|(2u<<15)|(2u<<18)|(2u<<21))
#define P1DX ((2u)|(1u<<3)|(3u<<6)|(2u<<9)|(2u<<12)|(2u<<15)|(2u<<18)|(2u<<21))

__global__ __launch_bounds__(256) void attn_kernel(const __hip_bfloat16* __restrict__ qkv,
                                                   __hip_bfloat16* __restrict__ ctx) {
    __shared__ __align__(16) short ks[16384];   // 64 pos x 256 ch (32 KB)
    __shared__ __align__(16) short vs[16384];   // 32 KB
    const int tid  = threadIdx.x;
    const int wave = tid >> 6, lane = tid & 63;
    const int bid  = blockIdx.x;
    const int b    = bid >> 8;
    const int rem  = bid & 255;
    const int ty   = rem >> 4;           // 16 y-tiles
    const int side = (rem >> 3) & 1;
    const int tx   = rem & 7;            // 8 x-tiles
    const int y0 = ty * 4, x0 = tx * 4;

    // ---- stage K/V for the 8x8 neighbor box (pos = yyl*8+xxl), XOR-swizzled chunks ----
    #pragma unroll
    for (int u = 0; u < 8; ++u) {
        const int q = u * 256 + tid;      // 0..2047
        const int pos = q >> 5;           // 0..63
        const int sl = q & 31;            // lds slot
        const int gc = (sl & 24) | ((sl & 7) ^ (pos & 7));
        const int yyl = pos >> 3, xxl = pos & 7;
        int yy = y0 - 2 + yyl; yy = yy < 0 ? 0 : (yy > 63 ? 63 : yy);
        int xx = x0 - 2 + xxl; xx = xx < 0 ? 0 : (xx > 31 ? 31 : xx);
        const int xm = side ? (31 - xx) : (63 - xx);
        const size_t tm = (size_t)((b << 12) + (yy << 6) + xm) * 768;
        async_copy16(qkv + tm + 256 + gc * 8, &ks[(u * 256 + wave * 64) * 8]);
        async_copy16(qkv + tm + 512 + gc * 8, &vs[(u * 256 + wave * 64) * 8]);
    }
    __syncthreads();

    // ---- compute: wave w -> row y0+w; loop 4 tokens in x ----
    const int n  = lane >> 3;
    const int cg = lane & 7;
    const int y  = y0 + wave;
    const int sh = 3 * n;
    const int dy0 = (int)((P0DY >> sh) & 7) - 2;
    const int dx0 = (int)((P0DX >> sh) & 7) - 2;
    const int dy1 = (int)((P1DY >> sh) & 7) - 2;
    const int dx1 = (int)((P1DX >> sh) & 7) - 2;

    for (int xl = 0; xl < 4; ++xl) {
        const int x = x0 + xl;
        const int t = (b << 12) + (y << 6) + side * 32 + x;
        bool valid[2];
        int pos[2];
        {
            const int yyA = y + dy0, xxA = x + dx0;
            valid[0] = yyA >= 0 && yyA < 64 && xxA >= 0 && xxA < 32;
            pos[0] = (wave + dy0 + 2) * 8 + (xl + dx0 + 2);      // always in [0,63]
            const int yyB = y + dy1, xxB = x + dx1;
            valid[1] = (n < 5) && yyB >= 0 && yyB < 64 && xxB >= 0 && xxB < 32;
            pos[1] = (wave + dy1 + 2) * 8 + (xl + dx1 + 2);
        }
        const size_t qb = (size_t)t * 768 + cg * 8;
        const size_t ob = (size_t)t * 256;

        #pragma unroll
        for (int hp = 0; hp < 2; ++hp) {
            bf16x8 q8[2], k8[2][2], v8[2][2];
            #pragma unroll
            for (int hh = 0; hh < 2; ++hh) {
                const int h = hp * 2 + hh;
                q8[hh] = *(const bf16x8*)(qkv + qb + h * 64);
                #pragma unroll
                for (int p = 0; p < 2; ++p) {
                    const int sl = h * 8 + (cg ^ (pos[p] & 7));
                    k8[hh][p] = *(const bf16x8*)(&ks[pos[p] * 256 + sl * 8]);
                    v8[hh][p] = *(const bf16x8*)(&vs[pos[p] * 256 + sl * 8]);
                }
            }
            #pragma unroll
            for (int hh = 0; hh < 2; ++hh) {
                float sc[2];
                #pragma unroll
                for (int p = 0; p < 2; ++p) {
                    float s = 0.f;
                    #pragma unroll
                    for (int j = 0; j < 8; ++j) s += b2f(q8[hh][j]) * b2f(k8[hh][p][j]);
                    s += __shfl_xor(s, 1, 64);
                    s += __shfl_xor(s, 2, 64);
                    s += __shfl_xor(s, 4, 64);
                    sc[p] = valid[p] ? s * 0.125f : -1e30f;
                }
                const float p0 = __expf(sc[0]);
                const float p1 = __expf(sc[1]);
                float l = p0 + p1;
                l += __shfl_xor(l, 8, 64);
                l += __shfl_xor(l, 16, 64);
                l += __shfl_xor(l, 32, 64);

                float o[8];
                #pragma unroll
                for (int j = 0; j < 8; ++j)
                    o[j] = p0 * b2f(v8[hh][0][j]) + p1 * b2f(v8[hh][1][j]);
                float r4[4];
                #pragma unroll
                for (int i = 0; i < 4; ++i) {
                    const float a = o[2 * i], bb = o[2 * i + 1];
                    const float mine = (n & 1) ? bb : a;
                    const float theirs = (n & 1) ? a : bb;
                    r4[i] = mine + __shfl_xor(theirs, 8, 64);
                }
                float r2[2];
                #pragma unroll
                for (int i = 0; i < 2; ++i) {
                    const float a = r4[2 * i], bb = r4[2 * i + 1];
                    const float mine = (n & 2) ? bb : a;
                    const float theirs = (n & 2) ? a : bb;
                    r2[i] = mine + __shfl_xor(theirs, 16, 64);
                }
                float ov;
                {
                    const float a = r2[0], bb = r2[1];
                    const float mine = (n & 4) ? bb : a;
                    const float theirs = (n & 4) ? a : bb;
                    ov = mine + __shfl_xor(theirs, 32, 64);
                }
                const float rl = __builtin_amdgcn_rcpf(l);
                ctx[ob + (hp * 2 + hh) * 64 + cg * 8 + n] = __float2bfloat16(ov * rl);
            }
        }
    }
}

// ---------------- fused: ctx2 = ctx@out_w^T+out_b (in LDS), then proj+LN+ReLU+store ----------------
// r1/r17 form verbatim (40.5us local optimum): 512 thr / 8 waves (2M x 4N), M=64, BK=64, 72KB.
__global__ __launch_bounds__(512, 4) void proj_ln_fused(const __hip_bfloat16* __restrict__ X,
                                                        const __hip_bfloat16* __restrict__ CTX,
                                                        const __hip_bfloat16* __restrict__ W2,
                                                        const float* __restrict__ out_b,
                                                        const __hip_bfloat16* __restrict__ W,
                                                        const float* __restrict__ bias,
                                                        const float* __restrict__ ln_g,
                                                        const float* __restrict__ ln_b,
                                                        float* __restrict__ out) {
    __shared__ __align__(16) short smem[36864];   // 72 KB
    __shared__ float mu_s[64], inv_s[64];
    short* c2s = smem;            // 64 x 256 (32 KB), persists through phase B
    short* As  = smem + 16384;    // 64 x 64 staging (8 KB)
    short* Bs  = smem + 20480;    // 256 x 64 staging (32 KB)
    const int tid = threadIdx.x;
    const int m0 = blockIdx.x * 64;
    const int b = m0 >> 12, sp0 = m0 & 4095;
    const int wave = tid >> 6, lane = tid & 63;
    const int wmh = (wave >> 2) * 32;   // M-half
    const int wn  = (wave & 3) * 64;    // N-quarter
    const int fm = lane & 15;
    const int fq = lane >> 4;

    // ---- phase A: ctx2 tile ----
    {
        f32x4 acc2[2][4] = {};
        for (int k0 = 0; k0 < 256; k0 += 64) {
            {   // ctx: 512 chunks, 1 per thread
                const int q = tid;
                const int r = q >> 3;
                const int cs = (q & 7) ^ (r & 7);
                async_copy16(CTX + (size_t)(m0 + r) * 256 + k0 + cs * 8, &As[(wave * 64) * 8]);
            }
            #pragma unroll
            for (int v = 0; v < 4; ++v) {          // out_w: 2048 chunks, 4 per thread
                const int q = v * 512 + tid;
                const int r = q >> 3;
                const int cs = (q & 7) ^ (r & 7);
                async_copy16(W2 + (size_t)r * 256 + k0 + cs * 8, &Bs[(v * 512 + wave * 64) * 8]);
            }
            __syncthreads();
            #pragma unroll
            for (int kk = 0; kk < 2; ++kk) {
                bf16x8 af[2], bw[4];
                #pragma unroll
                for (int i = 0; i < 2; ++i) {
                    const int row = wmh + i * 16 + fm;
                    af[i] = *(const bf16x8*)(&As[row * 64 + (((fq + kk * 4) ^ (fm & 7)) * 8)]);
                }
                #pragma unroll
                for (int j = 0; j < 4; ++j) {
                    const int row = wn + j * 16 + fm;
                    bw[j] = *(const bf16x8*)(&Bs[row * 64 + (((fq + kk * 4) ^ (fm & 7)) * 8)]);
                }
                #pragma unroll
                for (int i = 0; i < 2; ++i)
                    #pragma unroll
                    for (int j = 0; j < 4; ++j)
                        acc2[i][j] = __builtin_amdgcn_mfma_f32_16x16x32_bf16(af[i], bw[j], acc2[i][j], 0, 0, 0);
            }
            __syncthreads();
        }
        #pragma unroll
        for (int j = 0; j < 4; ++j) {
            const int col = wn + j * 16 + fm;
            const float bv = out_b[col];
            const int jch = col >> 3, cl = col & 7;
            #pragma unroll
            for (int i = 0; i < 2; ++i)
                #pragma unroll
                for (int rr = 0; rr < 4; ++rr) {
                    const int row = wmh + i * 16 + fq * 4 + rr;
                    const int slot = (jch & 24) | ((jch & 7) ^ (row & 7));
                    c2s[row * 256 + slot * 8 + cl] = f2b(acc2[i][j][rr] + bv);
                }
        }
    }
    __syncthreads();

    // ---- phase B: proj GEMM over K=1024 groups [q | c2 | |q-c2| | q*c2] ----
    f32x4 acc[2][4] = {};
    for (int k0 = 0; k0 < 1024; k0 += 64) {
        const int g = k0 >> 8;
        const int cb = k0 & 255;
        #pragma unroll
        for (int v = 0; v < 4; ++v) {              // proj_w: 2048 chunks, 4 per thread
            const int q = v * 512 + tid;
            const int r = q >> 3;
            const int cs = (q & 7) ^ (r & 7);
            async_copy16(W + (size_t)r * 1024 + k0 + cs * 8, &Bs[(v * 512 + wave * 64) * 8]);
        }
        if (g == 0) {
            const int q = tid;
            const int r = q >> 3;
            const int cs = (q & 7) ^ (r & 7);
            async_copy16(X + (size_t)(m0 + r) * 256 + cb + cs * 8, &As[(wave * 64) * 8]);
        } else if (g >= 2) {
            const int q = tid;
            const int r = q >> 3;
            const int cs = (q & 7) ^ (r & 7);
            int4 qraw = *(const int4*)(X + (size_t)(m0 + r) * 256 + cb + cs * 8);
            const int jch = (cb >> 3) + cs;
            const int slot = (jch & 24) | ((jch & 7) ^ (r & 7));
            int4 craw = *(const int4*)(&c2s[r * 256 + slot * 8]);
            const short* qs = (const short*)&qraw;
            const short* cw = (const short*)&craw;
            short tmp[8];
            #pragma unroll
            for (int j = 0; j < 8; ++j) {
                const float qv = b2f(qs[j]), cv = b2f(cw[j]);
                tmp[j] = f2b(g == 2 ? fabsf(qv - cv) : qv * cv);
            }
            *(int4*)(&As[q * 8]) = *(int4*)tmp;
        }
        // g == 1: no A staging — frags read straight from c2s
        __syncthreads();
        #pragma unroll
        for (int kk = 0; kk < 2; ++kk) {
            bf16x8 af[2], bw[4];
            if (g == 1) {
                #pragma unroll
                for (int i = 0; i < 2; ++i) {
                    const int row = wmh + i * 16 + fm;
                    const int jch = (cb >> 3) + fq + kk * 4;
                    const int slot = (jch & 24) | ((jch & 7) ^ (row & 7));
                    af[i] = *(const bf16x8*)(&c2s[row * 256 + slot * 8]);
                }
            } else {
                #pragma unroll
                for (int i = 0; i < 2; ++i) {
                    const int row = wmh + i * 16 + fm;
                    af[i] = *(const bf16x8*)(&As[row * 64 + (((fq + kk * 4) ^ (fm & 7)) * 8)]);
                }
            }
            #pragma unroll
            for (int j = 0; j < 4; ++j) {
                const int row = wn + j * 16 + fm;
                bw[j] = *(const bf16x8*)(&Bs[row * 64 + (((fq + kk * 4) ^ (fm & 7)) * 8)]);
            }
            #pragma unroll
            for (int i = 0; i < 2; ++i)
                #pragma unroll
                for (int j = 0; j < 4; ++j)
                    acc[i][j] = __builtin_amdgcn_mfma_f32_16x16x32_bf16(af[i], bw[j], acc[i][j], 0, 0, 0);
        }
        __syncthreads();
    }
    // ---- epilogue: ys (bf16, stride 266) overlays c2s/As (dead); LN; ReLU; store ----
    short* ys = smem;
    #pragma unroll
    for (int j = 0; j < 4; ++j) {
        const int col = wn + j * 16 + fm;
        const float bv = bias[col];
        #pragma unroll
        for (int i = 0; i < 2; ++i)
            #pragma unroll
            for (int r = 0; r < 4; ++r)
                ys[(wmh + i * 16 + fq * 4 + r) * 266 + col] = f2b(acc[i][j][r] + bv);
    }
    __syncthreads();
    {
        const int tt = tid >> 3, seg = tid & 7;   // 64 rows x 8 segs of 32
        float s = 0.f, ss = 0.f;
        #pragma unroll
        for (int j = 0; j < 32; ++j) {
            const float v = b2f(ys[tt * 266 + seg * 32 + j]);
            s += v; ss += v * v;
        }
        s += __shfl_xor(s, 1, 64);  ss += __shfl_xor(ss, 1, 64);
        s += __shfl_xor(s, 2, 64);  ss += __shfl_xor(ss, 2, 64);
        s += __shfl_xor(s, 4, 64);  ss += __shfl_xor(ss, 4, 64);
        if (seg == 0) {
            const float mu = s * (1.f / 256.f);
            const float var = ss * (1.f / 256.f) - mu * mu;
            mu_s[tt] = mu;
            inv_s[tt] = rsqrtf(var + 1e-5f);
        }
    }
    __syncthreads();
    {
        const int tl = tid & 63;
        const int j0 = tid >> 6;                  // 8 col-blocks of 32
        const float mu = mu_s[tl], inv = inv_s[tl];
        #pragma unroll
        for (int u = 0; u < 32; ++u) {
            const int j = j0 * 32 + u;
            const float v = (b2f(ys[tl * 266 + j]) - mu) * inv * ln_g[j] + ln_b[j];
            out[((size_t)(b * 256 + j) << 12) + sp0 + tl] = fmaxf(v, 0.f);
        }
    }
}

extern "C" void kernel_launch(void* const* d_in, const int* in_sizes, int n_in,
                              void* d_out, int out_size, void* d_ws, size_t ws_size,
                              hipStream_t stream) {
    (void)in_sizes; (void)n_in; (void)out_size; (void)ws_size;
    const float* feat   = (const float*)d_in[0];
    const float* in_w   = (const float*)d_in[1];
    const float* in_b   = (const float*)d_in[2];
    const float* out_w  = (const float*)d_in[3];
    const float* out_b  = (const float*)d_in[4];
    const float* proj_w = (const float*)d_in[5];
    const float* proj_b = (const float*)d_in[6];
    const float* ln_g   = (const float*)d_in[7];
    const float* ln_b   = (const float*)d_in[8];
    float* out = (float*)d_out;

    char* ws = (char*)d_ws;
    __hip_bfloat16* Xbf  = (__hip_bfloat16*)(ws);
    __hip_bfloat16* wbf  = (__hip_bfloat16*)(ws + (size_t)(16) * (1 << 20));
    __hip_bfloat16* qkv  = (__hip_bfloat16*)(ws + (size_t)(17) * (1 << 20));
    __hip_bfloat16* ctx  = (__hip_bfloat16*)(ws + (size_t)(65) * (1 << 20));
    __hip_bfloat16* in_wbf   = wbf;
    __hip_bfloat16* out_wbf  = wbf + 196608;
    __hip_bfloat16* proj_wbf = wbf + 262144;

    prep_kernel   <<<4352, 256, 0, stream>>>(feat, in_w, out_w, proj_w, Xbf, wbf);
    mfma_gemm<256, true><<<1536, 256, 0, stream>>>(Xbf, in_wbf, in_b, qkv, 768);
    attn_kernel   <<<2048, 256, 0, stream>>>(qkv, ctx);
    proj_ln_fused <<<NTOK / 64, 512, 0, stream>>>(Xbf, ctx, out_wbf, out_b,
                                                  proj_wbf, proj_b, ln_g, ln_b, out);
}

// Round 11
// 181.994 us; speedup vs baseline: 1.1370x; 1.1125x over previous
//
#include <hip/hip_runtime.h>
#include <hip/hip_bf16.h>

// ContralateralAttention, round 23: attn reverted to r7 wave-per-token (tiled attn was
// VALU-bound + 8-way LDS conflicts; old attn ~27us inferred). proj: r1 schedule with
// 256 thr / 4 waves, per-wave acc[4][4] (64x64) — halves per-CU ds_read traffic
// (192->128 b128/step) while KEEPING 2 blocks/CU (72KB, grid 512), the variable that
// r18 (1 blk/CU) lost. prep/gemm unchanged (r5 validated).
// ws layout (MB): Xbf [0,16) | wbf [16,17) | qkv [17,65) | ctx [65,81)

#define NTOK 32768

using bf16x8 = __attribute__((ext_vector_type(8))) short;
using f32x4  = __attribute__((ext_vector_type(4))) float;

__device__ __forceinline__ float b2f(short s) {
    unsigned u = ((unsigned)(unsigned short)s) << 16;
    union { unsigned u; float f; } c; c.u = u; return c.f;
}
__device__ __forceinline__ short f2b(float f) {
    __hip_bfloat16 h = __float2bfloat16(f);
    return *(short*)&h;
}
__device__ __forceinline__ void async_copy16(const void* g, void* l) {
    __builtin_amdgcn_global_load_lds(
        (const __attribute__((address_space(1))) unsigned int*)g,
        (__attribute__((address_space(3))) unsigned int*)l, 16, 0, 0);
}

// ---------------- prep: vectorized feat transpose+cast AND weight casts ----------------
__global__ __launch_bounds__(256) void prep_kernel(const float* __restrict__ feat,
                                                   const float* __restrict__ in_w,
                                                   const float* __restrict__ out_w,
                                                   const float* __restrict__ proj_w,
                                                   __hip_bfloat16* __restrict__ X,
                                                   __hip_bfloat16* __restrict__ wbf) {
    const int bid = blockIdx.x;
    const int tid = threadIdx.x;
    if (bid < 4096) {
        __shared__ float tile[32][68];
        const int b   = bid >> 9;
        const int rem = bid & 511;
        const int sp0 = (rem & 63) * 64;
        const int c0  = (rem >> 6) * 32;
        #pragma unroll
        for (int u = 0; u < 2; ++u) {
            const int idx = tid + u * 256;      // 0..511
            const int cl = idx >> 4;            // 0..31
            const int sq = (idx & 15) * 4;      // 0..60
            const float4 v = *(const float4*)(feat + ((size_t)(b * 256 + c0 + cl) << 12) + sp0 + sq);
            tile[cl][sq]     = v.x;
            tile[cl][sq + 1] = v.y;
            tile[cl][sq + 2] = v.z;
            tile[cl][sq + 3] = v.w;
        }
        __syncthreads();
        #pragma unroll
        for (int u = 0; u < 2; ++u) {
            const int idx = tid + u * 256;      // 0..511
            const int tok = idx >> 3;           // 0..63
            const int cq  = (idx & 7) * 4;      // 0..28
            short4 s;
            s.x = f2b(tile[cq][tok]);
            s.y = f2b(tile[cq + 1][tok]);
            s.z = f2b(tile[cq + 2][tok]);
            s.w = f2b(tile[cq + 3][tok]);
            *(short4*)(X + (size_t)(b * 4096 + sp0 + tok) * 256 + c0 + cq) = s;
        }
    } else {
        const int i4 = (bid - 4096) * 1024 + tid * 4;
        if (i4 < 196608) {
            const float4 v = *(const float4*)(in_w + i4);
            short4 s = {f2b(v.x), f2b(v.y), f2b(v.z), f2b(v.w)};
            *(short4*)(wbf + i4) = s;
        }
        if (i4 < 65536) {
            const float4 v = *(const float4*)(out_w + i4);
            short4 s = {f2b(v.x), f2b(v.y), f2b(v.z), f2b(v.w)};
            *(short4*)(wbf + 196608 + i4) = s;
        }
        if (i4 < 262144) {
            const float4 v = *(const float4*)(proj_w + i4);
            short4 s = {f2b(v.x), f2b(v.y), f2b(v.z), f2b(v.w)};
            *(short4*)(wbf + 262144 + i4) = s;
        }
    }
}

// ---------------- MFMA GEMM (qkv): 256 thr, M=128 x N=128, BK=64, 2-phase dbuf ----------------
// 1D grid 1536, XCD-chunked work order: work=(bid&7)*192+(bid>>3); xb=work/6 (A-tile), yb=work%6.
template <int KDIM, bool OUT_BF16>
__global__ __launch_bounds__(256) void mfma_gemm(const __hip_bfloat16* __restrict__ A,
                                                 const __hip_bfloat16* __restrict__ W,
                                                 const float* __restrict__ bias,
                                                 void* __restrict__ C, int Ntot) {
    __shared__ __align__(16) short As[2][128 * 64];   // 2 x 16 KB
    __shared__ __align__(16) short Bs[2][128 * 64];   // 2 x 16 KB
    const int tid = threadIdx.x;
    const int work = (blockIdx.x & 7) * 192 + (blockIdx.x >> 3);
    const int m0 = (work / 6) * 128;
    const int n0 = (work % 6) * 128;
    const int wave = tid >> 6, lane = tid & 63;
    const int wm = (wave >> 1) * 64;
    const int wn = (wave & 1) * 64;
    const int fm = lane & 15;
    const int fq = lane >> 4;

    // prologue: stage K-slice 0 into buffer 0
    #pragma unroll
    for (int v = 0; v < 4; ++v) {
        const int qb = v * 256 + wave * 64;
        const int q = qb + lane;
        const int r = q >> 3;
        const int cs = (q & 7) ^ (r & 7);
        async_copy16(A + (size_t)(m0 + r) * KDIM + cs * 8, &As[0][qb * 8]);
        async_copy16(W + (size_t)(n0 + r) * KDIM + cs * 8, &Bs[0][qb * 8]);
    }
    __syncthreads();

    f32x4 acc[4][4] = {};
    #pragma unroll
    for (int t = 0; t < KDIM / 64; ++t) {
        const int cur = t & 1;
        if (t + 1 < KDIM / 64) {                       // issue next-slice stage FIRST
            #pragma unroll
            for (int v = 0; v < 4; ++v) {
                const int qb = v * 256 + wave * 64;
                const int q = qb + lane;
                const int r = q >> 3;
                const int cs = (q & 7) ^ (r & 7);
                async_copy16(A + (size_t)(m0 + r) * KDIM + (t + 1) * 64 + cs * 8, &As[cur ^ 1][qb * 8]);
                async_copy16(W + (size_t)(n0 + r) * KDIM + (t + 1) * 64 + cs * 8, &Bs[cur ^ 1][qb * 8]);
            }
        }
        #pragma unroll
        for (int kk = 0; kk < 2; ++kk) {
            bf16x8 af[4], bw[4];
            #pragma unroll
            for (int i = 0; i < 4; ++i) {
                const int row = wm + i * 16 + fm;
                af[i] = *(const bf16x8*)(&As[cur][row * 64 + (((fq + kk * 4) ^ (fm & 7)) * 8)]);
            }
            #pragma unroll
            for (int j = 0; j < 4; ++j) {
                const int row = wn + j * 16 + fm;
                bw[j] = *(const bf16x8*)(&Bs[cur][row * 64 + (((fq + kk * 4) ^ (fm & 7)) * 8)]);
            }
            #pragma unroll
            for (int i = 0; i < 4; ++i)
                #pragma unroll
                for (int j = 0; j < 4; ++j)
                    acc[i][j] = __builtin_amdgcn_mfma_f32_16x16x32_bf16(af[i], bw[j], acc[i][j], 0, 0, 0);
        }
        __syncthreads();                               // one barrier per K-step
    }
    #pragma unroll
    for (int j = 0; j < 4; ++j) {
        const int col = n0 + wn + j * 16 + fm;
        const float bv = bias[col];
        #pragma unroll
        for (int i = 0; i < 4; ++i) {
            #pragma unroll
            for (int r = 0; r < 4; ++r) {
                const int row = m0 + wm + i * 16 + fq * 4 + r;
                const float v = acc[i][j][r] + bv;
                if (OUT_BF16)
                    ((__hip_bfloat16*)C)[(size_t)row * Ntot + col] = __float2bfloat16(v);
                else
                    ((float*)C)[(size_t)row * Ntot + col] = v;
            }
        }
    }
}

// ---------------- sparse attention (r7 form, validated, ~27us) ----------------
#define P0DY ((2u)|(2u<<3)|(2u<<6)|(2u<<9)|(2u<<12)|(1u<<15)|(1u<<18)|(1u<<21))
#define P0DX ((2u)|(1u<<3)|(3u<<6)|(0u<<9)|(4u<<12)|(2u<<15)|(1u<<18)|(3u<<21))
#define P1DY ((3u)|(3u<<3)|(3u<<6)|(0u<<9)|(4u<<12)|(2u<<15)|(2u<<18)|(2u<<21))
#define P1DX ((2u)|(1u<<3)|(3u<<6)|(2u<<9)|(2u<<12)|(2u<<15)|(2u<<18)|(2u<<21))

__global__ __launch_bounds__(256) void attn_kernel(const __hip_bfloat16* __restrict__ qkv,
                                                   __hip_bfloat16* __restrict__ ctx) {
    const int t = blockIdx.x * 4 + (threadIdx.x >> 6);
    const int lane = threadIdx.x & 63;
    const int n  = lane >> 3;
    const int cg = lane & 7;
    const int x6 = t & 63;
    const int yq = (t >> 6) & 63;
    const int b  = t >> 12;
    const int side = x6 >> 5;
    const int x = x6 & 31;

    bool valid[2];
    size_t kb[2];
    #pragma unroll
    for (int p = 0; p < 2; ++p) {
        const unsigned dyp = p ? P1DY : P0DY;
        const unsigned dxp = p ? P1DX : P0DX;
        const int sh = 3 * n;
        const int dy = (int)((dyp >> sh) & 7) - 2;
        const int dx = (int)((dxp >> sh) & 7) - 2;
        const int yy = yq + dy, xx = x + dx;
        valid[p] = (p == 0 || n < 5) && yy >= 0 && yy < 64 && xx >= 0 && xx < 32;
        const int xm = side ? (31 - xx) : (63 - xx);
        int tm = (b << 12) + (yy << 6) + xm;
        if (!valid[p]) tm = t;
        kb[p] = (size_t)tm * 768 + 256 + cg * 8;
    }
    const size_t qb = (size_t)t * 768 + cg * 8;
    const size_t ob = (size_t)t * 256;

    #pragma unroll
    for (int hp = 0; hp < 2; ++hp) {
        bf16x8 q8[2], k8[2][2], v8[2][2];
        #pragma unroll
        for (int hh = 0; hh < 2; ++hh) {
            const int h = hp * 2 + hh;
            q8[hh] = *(const bf16x8*)(qkv + qb + h * 64);
            #pragma unroll
            for (int p = 0; p < 2; ++p) {
                k8[hh][p] = *(const bf16x8*)(qkv + kb[p] + h * 64);
                v8[hh][p] = *(const bf16x8*)(qkv + kb[p] + h * 64 + 256);
            }
        }
        #pragma unroll
        for (int hh = 0; hh < 2; ++hh) {
            float sc[2];
            #pragma unroll
            for (int p = 0; p < 2; ++p) {
                float s = 0.f;
                #pragma unroll
                for (int j = 0; j < 8; ++j) s += b2f(q8[hh][j]) * b2f(k8[hh][p][j]);
                s += __shfl_xor(s, 1, 64);
                s += __shfl_xor(s, 2, 64);
                s += __shfl_xor(s, 4, 64);
                sc[p] = valid[p] ? s * 0.125f : -1e30f;
            }
            const float p0 = __expf(sc[0]);
            const float p1 = __expf(sc[1]);
            float l = p0 + p1;
            l += __shfl_xor(l, 8, 64);
            l += __shfl_xor(l, 16, 64);
            l += __shfl_xor(l, 32, 64);

            float o[8];
            #pragma unroll
            for (int j = 0; j < 8; ++j)
                o[j] = p0 * b2f(v8[hh][0][j]) + p1 * b2f(v8[hh][1][j]);
            float r4[4];
            #pragma unroll
            for (int i = 0; i < 4; ++i) {
                const float a = o[2 * i], bb = o[2 * i + 1];
                const float mine = (n & 1) ? bb : a;
                const float theirs = (n & 1) ? a : bb;
                r4[i] = mine + __shfl_xor(theirs, 8, 64);
            }
            float r2[2];
            #pragma unroll
            for (int i = 0; i < 2; ++i) {
                const float a = r4[2 * i], bb = r4[2 * i + 1];
                const float mine = (n & 2) ? bb : a;
                const float theirs = (n & 2) ? a : bb;
                r2[i] = mine + __shfl_xor(theirs, 16, 64);
            }
            float ov;
            {
                const float a = r2[0], bb = r2[1];
                const float mine = (n & 4) ? bb : a;
                const float theirs = (n & 4) ? a : bb;
                ov = mine + __shfl_xor(theirs, 32, 64);
            }
            const float rl = __builtin_amdgcn_rcpf(l);
            ctx[ob + (hp * 2 + hh) * 64 + cg * 8 + n] = __float2bfloat16(ov * rl);
        }
    }
}

// ---------------- fused: ctx2 = ctx@out_w^T+out_b (in LDS), then proj+LN+ReLU+store ----------------
// r23: r1 schedule, 256 thr / 4 waves, per-wave acc[4][4] (64x64 output). 72KB, grid 512
// -> 2 blocks/CU kept; per-CU ds_read traffic 192->128 b128/step.
__global__ __launch_bounds__(256, 2) void proj_ln_fused(const __hip_bfloat16* __restrict__ X,
                                                        const __hip_bfloat16* __restrict__ CTX,
                                                        const __hip_bfloat16* __restrict__ W2,
                                                        const float* __restrict__ out_b,
                                                        const __hip_bfloat16* __restrict__ W,
                                                        const float* __restrict__ bias,
                                                        const float* __restrict__ ln_g,
                                                        const float* __restrict__ ln_b,
                                                        float* __restrict__ out) {
    __shared__ __align__(16) short smem[36864];   // 72 KB
    __shared__ float mu_s[64], inv_s[64];
    short* c2s = smem;            // 64 x 256 (32 KB), persists through phase B
    short* As  = smem + 16384;    // 64 x 64 staging (8 KB)
    short* Bs  = smem + 20480;    // 256 x 64 staging (32 KB)
    const int tid = threadIdx.x;
    const int m0 = blockIdx.x * 64;
    const int b = m0 >> 12, sp0 = m0 & 4095;
    const int wave = tid >> 6, lane = tid & 63;
    const int wn = wave * 64;           // N-quarter; each wave spans all 64 M-rows
    const int fm = lane & 15;
    const int fq = lane >> 4;

    // ---- phase A: ctx2 tile ----
    {
        f32x4 acc2[4][4] = {};
        for (int k0 = 0; k0 < 256; k0 += 64) {
            #pragma unroll
            for (int v = 0; v < 2; ++v) {          // ctx: 512 chunks, 2 per thread
                const int q = v * 256 + tid;
                const int r = q >> 3;
                const int cs = (q & 7) ^ (r & 7);
                async_copy16(CTX + (size_t)(m0 + r) * 256 + k0 + cs * 8, &As[(v * 256 + wave * 64) * 8]);
            }
            #pragma unroll
            for (int v = 0; v < 8; ++v) {          // out_w: 2048 chunks, 8 per thread
                const int q = v * 256 + tid;
                const int r = q >> 3;
                const int cs = (q & 7) ^ (r & 7);
                async_copy16(W2 + (size_t)r * 256 + k0 + cs * 8, &Bs[(v * 256 + wave * 64) * 8]);
            }
            __syncthreads();
            #pragma unroll
            for (int kk = 0; kk < 2; ++kk) {
                bf16x8 af[4], bw[4];
                #pragma unroll
                for (int i = 0; i < 4; ++i) {
                    const int row = i * 16 + fm;
                    af[i] = *(const bf16x8*)(&As[row * 64 + (((fq + kk * 4) ^ (fm & 7)) * 8)]);
                }
                #pragma unroll
                for (int j = 0; j < 4; ++j) {
                    const int row = wn + j * 16 + fm;
                    bw[j] = *(const bf16x8*)(&Bs[row * 64 + (((fq + kk * 4) ^ (fm & 7)) * 8)]);
                }
                #pragma unroll
                for (int i = 0; i < 4; ++i)
                    #pragma unroll
                    for (int j = 0; j < 4; ++j)
                        acc2[i][j] = __builtin_amdgcn_mfma_f32_16x16x32_bf16(af[i], bw[j], acc2[i][j], 0, 0, 0);
            }
            __syncthreads();
        }
        #pragma unroll
        for (int j = 0; j < 4; ++j) {
            const int col = wn + j * 16 + fm;
            const float bv = out_b[col];
            const int jch = col >> 3, cl = col & 7;
            #pragma unroll
            for (int i = 0; i < 4; ++i)
                #pragma unroll
                for (int rr = 0; rr < 4; ++rr) {
                    const int row = i * 16 + fq * 4 + rr;
                    const int slot = (jch & 24) | ((jch & 7) ^ (row & 7));
                    c2s[row * 256 + slot * 8 + cl] = f2b(acc2[i][j][rr] + bv);
                }
        }
    }
    __syncthreads();

    // ---- phase B: proj GEMM over K=1024 groups [q | c2 | |q-c2| | q*c2] ----
    f32x4 acc[4][4] = {};
    for (int k0 = 0; k0 < 1024; k0 += 64) {
        const int g = k0 >> 8;
        const int cb = k0 & 255;
        #pragma unroll
        for (int v = 0; v < 8; ++v) {              // proj_w: 2048 chunks, 8 per thread
            const int q = v * 256 + tid;
            const int r = q >> 3;
            const int cs = (q & 7) ^ (r & 7);
            async_copy16(W + (size_t)r * 1024 + k0 + cs * 8, &Bs[(v * 256 + wave * 64) * 8]);
        }
        if (g == 0) {
            #pragma unroll
            for (int v = 0; v < 2; ++v) {
                const int q = v * 256 + tid;
                const int r = q >> 3;
                const int cs = (q & 7) ^ (r & 7);
                async_copy16(X + (size_t)(m0 + r) * 256 + cb + cs * 8, &As[(v * 256 + wave * 64) * 8]);
            }
        } else if (g >= 2) {
            #pragma unroll
            for (int v = 0; v < 2; ++v) {
                const int q = v * 256 + tid;
                const int r = q >> 3;
                const int cs = (q & 7) ^ (r & 7);
                int4 qraw = *(const int4*)(X + (size_t)(m0 + r) * 256 + cb + cs * 8);
                const int jch = (cb >> 3) + cs;
                const int slot = (jch & 24) | ((jch & 7) ^ (r & 7));
                int4 craw = *(const int4*)(&c2s[r * 256 + slot * 8]);
                const short* qs = (const short*)&qraw;
                const short* cw = (const short*)&craw;
                short tmp[8];
                #pragma unroll
                for (int j = 0; j < 8; ++j) {
                    const float qv = b2f(qs[j]), cv = b2f(cw[j]);
                    tmp[j] = f2b(g == 2 ? fabsf(qv - cv) : qv * cv);
                }
                *(int4*)(&As[q * 8]) = *(int4*)tmp;
            }
        }
        // g == 1: no A staging — frags read straight from c2s
        __syncthreads();
        #pragma unroll
        for (int kk = 0; kk < 2; ++kk) {
            bf16x8 af[4], bw[4];
            if (g == 1) {
                #pragma unroll
                for (int i = 0; i < 4; ++i) {
                    const int row = i * 16 + fm;
                    const int jch = (cb >> 3) + fq + kk * 4;
                    const int slot = (jch & 24) | ((jch & 7) ^ (row & 7));
                    af[i] = *(const bf16x8*)(&c2s[row * 256 + slot * 8]);
                }
            } else {
                #pragma unroll
                for (int i = 0; i < 4; ++i) {
                    const int row = i * 16 + fm;
                    af[i] = *(const bf16x8*)(&As[row * 64 + (((fq + kk * 4) ^ (fm & 7)) * 8)]);
                }
            }
            #pragma unroll
            for (int j = 0; j < 4; ++j) {
                const int row = wn + j * 16 + fm;
                bw[j] = *(const bf16x8*)(&Bs[row * 64 + (((fq + kk * 4) ^ (fm & 7)) * 8)]);
            }
            #pragma unroll
            for (int i = 0; i < 4; ++i)
                #pragma unroll
                for (int j = 0; j < 4; ++j)
                    acc[i][j] = __builtin_amdgcn_mfma_f32_16x16x32_bf16(af[i], bw[j], acc[i][j], 0, 0, 0);
        }
        __syncthreads();
    }
    // ---- epilogue: ys (bf16, stride 266) overlays c2s/As (dead); LN; ReLU; store ----
    short* ys = smem;
    #pragma unroll
    for (int j = 0; j < 4; ++j) {
        const int col = wn + j * 16 + fm;
        const float bv = bias[col];
        #pragma unroll
        for (int i = 0; i < 4; ++i)
            #pragma unroll
            for (int r = 0; r < 4; ++r)
                ys[(i * 16 + fq * 4 + r) * 266 + col] = f2b(acc[i][j][r] + bv);
    }
    __syncthreads();
    {
        const int tt = tid >> 2, seg = tid & 3;   // 64 rows x 4 segs of 64
        float s = 0.f, ss = 0.f;
        #pragma unroll
        for (int j = 0; j < 64; ++j) {
            const float v = b2f(ys[tt * 266 + seg * 64 + j]);
            s += v; ss += v * v;
        }
        s += __shfl_xor(s, 1, 64);  ss += __shfl_xor(ss, 1, 64);
        s += __shfl_xor(s, 2, 64);  ss += __shfl_xor(ss, 2, 64);
        if (seg == 0) {
            const float mu = s * (1.f / 256.f);
            const float var = ss * (1.f / 256.f) - mu * mu;
            mu_s[tt] = mu;
            inv_s[tt] = rsqrtf(var + 1e-5f);
        }
    }
    __syncthreads();
    {
        const int tl = tid & 63;                  // row 0..63
        const int j0 = tid >> 6;                  // 4 col-blocks of 64
        const float mu = mu_s[tl], inv = inv_s[tl];
        #pragma unroll
        for (int u = 0; u < 64; ++u) {
            const int j = j0 * 64 + u;
            const float v = (b2f(ys[tl * 266 + j]) - mu) * inv * ln_g[j] + ln_b[j];
            out[((size_t)(b * 256 + j) << 12) + sp0 + tl] = fmaxf(v, 0.f);
        }
    }
}

extern "C" void kernel_launch(void* const* d_in, const int* in_sizes, int n_in,
                              void* d_out, int out_size, void* d_ws, size_t ws_size,
                              hipStream_t stream) {
    (void)in_sizes; (void)n_in; (void)out_size; (void)ws_size;
    const float* feat   = (const float*)d_in[0];
    const float* in_w   = (const float*)d_in[1];
    const float* in_b   = (const float*)d_in[2];
    const float* out_w  = (const float*)d_in[3];
    const float* out_b  = (const float*)d_in[4];
    const float* proj_w = (const float*)d_in[5];
    const float* proj_b = (const float*)d_in[6];
    const float* ln_g   = (const float*)d_in[7];
    const float* ln_b   = (const float*)d_in[8];
    float* out = (float*)d_out;

    char* ws = (char*)d_ws;
    __hip_bfloat16* Xbf  = (__hip_bfloat16*)(ws);
    __hip_bfloat16* wbf  = (__hip_bfloat16*)(ws + (size_t)(16) * (1 << 20));
    __hip_bfloat16* qkv  = (__hip_bfloat16*)(ws + (size_t)(17) * (1 << 20));
    __hip_bfloat16* ctx  = (__hip_bfloat16*)(ws + (size_t)(65) * (1 << 20));
    __hip_bfloat16* in_wbf   = wbf;
    __hip_bfloat16* out_wbf  = wbf + 196608;
    __hip_bfloat16* proj_wbf = wbf + 262144;

    prep_kernel   <<<4352, 256, 0, stream>>>(feat, in_w, out_w, proj_w, Xbf, wbf);
    mfma_gemm<256, true><<<1536, 256, 0, stream>>>(Xbf, in_wbf, in_b, qkv, 768);
    attn_kernel   <<<NTOK / 4, 256, 0, stream>>>(qkv, ctx);
    proj_ln_fused <<<NTOK / 64, 256, 0, stream>>>(Xbf, ctx, out_wbf, out_b,
                                                  proj_wbf, proj_b, ln_g, ln_b, out);
}

// Round 12
// 179.368 us; speedup vs baseline: 1.1536x; 1.0146x over previous
//
#include <hip/hip_runtime.h>
#include <hip/hip_bf16.h>

// ContralateralAttention, round 24: attn inner math -> v_dot2_f32_bf16 (dot9) + v_perm_b32.
// QK: bf16x8 dot = 4 dot2 ops, zero repacking (pairs already share u32 words). PV: perm-pack
// (v0[j],v1[j]) + dot2 vs packed bf16 (p0,p1) = 2 ops/elem vs 4. __has_builtin guards with
// scalar fallback -> compiles to current code if builtins absent. p bf16-quantized only in PV
// (~0.4% rel on ctx; absmax headroom 3x).
// proj/prep/gemm byte-identical to round-11 kernel (validated 182.0; proj 40.68 = structural floor).
// ws layout (MB): Xbf [0,16) | wbf [16,17) | qkv [17,65) | ctx [65,81)

#define NTOK 32768

using bf16x8 = __attribute__((ext_vector_type(8))) short;
using f32x4  = __attribute__((ext_vector_type(4))) float;
using u32x4  = __attribute__((ext_vector_type(4))) unsigned;

__device__ __forceinline__ float b2f(short s) {
    unsigned u = ((unsigned)(unsigned short)s) << 16;
    union { unsigned u; float f; } c; c.u = u; return c.f;
}
__device__ __forceinline__ short f2b(float f) {
    __hip_bfloat16 h = __float2bfloat16(f);
    return *(short*)&h;
}
__device__ __forceinline__ float dot2bf(unsigned a, unsigned b, float c) {
#if __has_builtin(__builtin_amdgcn_fdot2_f32_bf16)
    typedef __bf16 bf2 __attribute__((ext_vector_type(2)));
    return __builtin_amdgcn_fdot2_f32_bf16(__builtin_bit_cast(bf2, a),
                                           __builtin_bit_cast(bf2, b), c, false);
#else
    union { unsigned u; short s[2]; } ua, ub;
    ua.u = a; ub.u = b;
    return c + b2f(ua.s[0]) * b2f(ub.s[0]) + b2f(ua.s[1]) * b2f(ub.s[1]);
#endif
}
__device__ __forceinline__ unsigned permb(unsigned a, unsigned b, unsigned s) {
#if __has_builtin(__builtin_amdgcn_perm)
    return __builtin_amdgcn_perm(a, b, s);
#else
    unsigned long long v = ((unsigned long long)a << 32) | b;
    unsigned r = 0;
    #pragma unroll
    for (int i = 0; i < 4; ++i) r |= (unsigned)((v >> (((s >> (8 * i)) & 7) * 8)) & 0xff) << (8 * i);
    return r;
#endif
}
__device__ __forceinline__ void async_copy16(const void* g, void* l) {
    __builtin_amdgcn_global_load_lds(
        (const __attribute__((address_space(1))) unsigned int*)g,
        (__attribute__((address_space(3))) unsigned int*)l, 16, 0, 0);
}

// ---------------- prep: vectorized feat transpose+cast AND weight casts ----------------
__global__ __launch_bounds__(256) void prep_kernel(const float* __restrict__ feat,
                                                   const float* __restrict__ in_w,
                                                   const float* __restrict__ out_w,
                                                   const float* __restrict__ proj_w,
                                                   __hip_bfloat16* __restrict__ X,
                                                   __hip_bfloat16* __restrict__ wbf) {
    const int bid = blockIdx.x;
    const int tid = threadIdx.x;
    if (bid < 4096) {
        __shared__ float tile[32][68];
        const int b   = bid >> 9;
        const int rem = bid & 511;
        const int sp0 = (rem & 63) * 64;
        const int c0  = (rem >> 6) * 32;
        #pragma unroll
        for (int u = 0; u < 2; ++u) {
            const int idx = tid + u * 256;      // 0..511
            const int cl = idx >> 4;            // 0..31
            const int sq = (idx & 15) * 4;      // 0..60
            const float4 v = *(const float4*)(feat + ((size_t)(b * 256 + c0 + cl) << 12) + sp0 + sq);
            tile[cl][sq]     = v.x;
            tile[cl][sq + 1] = v.y;
            tile[cl][sq + 2] = v.z;
            tile[cl][sq + 3] = v.w;
        }
        __syncthreads();
        #pragma unroll
        for (int u = 0; u < 2; ++u) {
            const int idx = tid + u * 256;      // 0..511
            const int tok = idx >> 3;           // 0..63
            const int cq  = (idx & 7) * 4;      // 0..28
            short4 s;
            s.x = f2b(tile[cq][tok]);
            s.y = f2b(tile[cq + 1][tok]);
            s.z = f2b(tile[cq + 2][tok]);
            s.w = f2b(tile[cq + 3][tok]);
            *(short4*)(X + (size_t)(b * 4096 + sp0 + tok) * 256 + c0 + cq) = s;
        }
    } else {
        const int i4 = (bid - 4096) * 1024 + tid * 4;
        if (i4 < 196608) {
            const float4 v = *(const float4*)(in_w + i4);
            short4 s = {f2b(v.x), f2b(v.y), f2b(v.z), f2b(v.w)};
            *(short4*)(wbf + i4) = s;
        }
        if (i4 < 65536) {
            const float4 v = *(const float4*)(out_w + i4);
            short4 s = {f2b(v.x), f2b(v.y), f2b(v.z), f2b(v.w)};
            *(short4*)(wbf + 196608 + i4) = s;
        }
        if (i4 < 262144) {
            const float4 v = *(const float4*)(proj_w + i4);
            short4 s = {f2b(v.x), f2b(v.y), f2b(v.z), f2b(v.w)};
            *(short4*)(wbf + 262144 + i4) = s;
        }
    }
}

// ---------------- MFMA GEMM (qkv): 256 thr, M=128 x N=128, BK=64, 2-phase dbuf ----------------
// 1D grid 1536, XCD-chunked work order: work=(bid&7)*192+(bid>>3); xb=work/6 (A-tile), yb=work%6.
template <int KDIM, bool OUT_BF16>
__global__ __launch_bounds__(256) void mfma_gemm(const __hip_bfloat16* __restrict__ A,
                                                 const __hip_bfloat16* __restrict__ W,
                                                 const float* __restrict__ bias,
                                                 void* __restrict__ C, int Ntot) {
    __shared__ __align__(16) short As[2][128 * 64];   // 2 x 16 KB
    __shared__ __align__(16) short Bs[2][128 * 64];   // 2 x 16 KB
    const int tid = threadIdx.x;
    const int work = (blockIdx.x & 7) * 192 + (blockIdx.x >> 3);
    const int m0 = (work / 6) * 128;
    const int n0 = (work % 6) * 128;
    const int wave = tid >> 6, lane = tid & 63;
    const int wm = (wave >> 1) * 64;
    const int wn = (wave & 1) * 64;
    const int fm = lane & 15;
    const int fq = lane >> 4;

    // prologue: stage K-slice 0 into buffer 0
    #pragma unroll
    for (int v = 0; v < 4; ++v) {
        const int qb = v * 256 + wave * 64;
        const int q = qb + lane;
        const int r = q >> 3;
        const int cs = (q & 7) ^ (r & 7);
        async_copy16(A + (size_t)(m0 + r) * KDIM + cs * 8, &As[0][qb * 8]);
        async_copy16(W + (size_t)(n0 + r) * KDIM + cs * 8, &Bs[0][qb * 8]);
    }
    __syncthreads();

    f32x4 acc[4][4] = {};
    #pragma unroll
    for (int t = 0; t < KDIM / 64; ++t) {
        const int cur = t & 1;
        if (t + 1 < KDIM / 64) {                       // issue next-slice stage FIRST
            #pragma unroll
            for (int v = 0; v < 4; ++v) {
                const int qb = v * 256 + wave * 64;
                const int q = qb + lane;
                const int r = q >> 3;
                const int cs = (q & 7) ^ (r & 7);
                async_copy16(A + (size_t)(m0 + r) * KDIM + (t + 1) * 64 + cs * 8, &As[cur ^ 1][qb * 8]);
                async_copy16(W + (size_t)(n0 + r) * KDIM + (t + 1) * 64 + cs * 8, &Bs[cur ^ 1][qb * 8]);
            }
        }
        #pragma unroll
        for (int kk = 0; kk < 2; ++kk) {
            bf16x8 af[4], bw[4];
            #pragma unroll
            for (int i = 0; i < 4; ++i) {
                const int row = wm + i * 16 + fm;
                af[i] = *(const bf16x8*)(&As[cur][row * 64 + (((fq + kk * 4) ^ (fm & 7)) * 8)]);
            }
            #pragma unroll
            for (int j = 0; j < 4; ++j) {
                const int row = wn + j * 16 + fm;
                bw[j] = *(const bf16x8*)(&Bs[cur][row * 64 + (((fq + kk * 4) ^ (fm & 7)) * 8)]);
            }
            #pragma unroll
            for (int i = 0; i < 4; ++i)
                #pragma unroll
                for (int j = 0; j < 4; ++j)
                    acc[i][j] = __builtin_amdgcn_mfma_f32_16x16x32_bf16(af[i], bw[j], acc[i][j], 0, 0, 0);
        }
        __syncthreads();                               // one barrier per K-step
    }
    #pragma unroll
    for (int j = 0; j < 4; ++j) {
        const int col = n0 + wn + j * 16 + fm;
        const float bv = bias[col];
        #pragma unroll
        for (int i = 0; i < 4; ++i) {
            #pragma unroll
            for (int r = 0; r < 4; ++r) {
                const int row = m0 + wm + i * 16 + fq * 4 + r;
                const float v = acc[i][j][r] + bv;
                if (OUT_BF16)
                    ((__hip_bfloat16*)C)[(size_t)row * Ntot + col] = __float2bfloat16(v);
                else
                    ((float*)C)[(size_t)row * Ntot + col] = v;
            }
        }
    }
}

// ---------------- sparse attention (r7 dataflow; dot2/perm inner math) ----------------
#define P0DY ((2u)|(2u<<3)|(2u<<6)|(2u<<9)|(2u<<12)|(1u<<15)|(1u<<18)|(1u<<21))
#define P0DX ((2u)|(1u<<3)|(3u<<6)|(0u<<9)|(4u<<12)|(2u<<15)|(1u<<18)|(3u<<21))
#define P1DY ((3u)|(3u<<3)|(3u<<6)|(0u<<9)|(4u<<12)|(2u<<15)|(2u<<18)|(2u<<21))
#define P1DX ((2u)|(1u<<3)|(3u<<6)|(2u<<9)|(2u<<12)|(2u<<15)|(2u<<18)|(2u<<21))

__global__ __launch_bounds__(256) void attn_kernel(const __hip_bfloat16* __restrict__ qkv,
                                                   __hip_bfloat16* __restrict__ ctx) {
    const int t = blockIdx.x * 4 + (threadIdx.x >> 6);
    const int lane = threadIdx.x & 63;
    const int n  = lane >> 3;
    const int cg = lane & 7;
    const int x6 = t & 63;
    const int yq = (t >> 6) & 63;
    const int b  = t >> 12;
    const int side = x6 >> 5;
    const int x = x6 & 31;

    bool valid[2];
    size_t kb[2];
    #pragma unroll
    for (int p = 0; p < 2; ++p) {
        const unsigned dyp = p ? P1DY : P0DY;
        const unsigned dxp = p ? P1DX : P0DX;
        const int sh = 3 * n;
        const int dy = (int)((dyp >> sh) & 7) - 2;
        const int dx = (int)((dxp >> sh) & 7) - 2;
        const int yy = yq + dy, xx = x + dx;
        valid[p] = (p == 0 || n < 5) && yy >= 0 && yy < 64 && xx >= 0 && xx < 32;
        const int xm = side ? (31 - xx) : (63 - xx);
        int tm = (b << 12) + (yy << 6) + xm;
        if (!valid[p]) tm = t;
        kb[p] = (size_t)tm * 768 + 256 + cg * 8;
    }
    const size_t qb = (size_t)t * 768 + cg * 8;
    const size_t ob = (size_t)t * 256;

    #pragma unroll
    for (int hp = 0; hp < 2; ++hp) {
        bf16x8 q8[2], k8[2][2], v8[2][2];
        #pragma unroll
        for (int hh = 0; hh < 2; ++hh) {
            const int h = hp * 2 + hh;
            q8[hh] = *(const bf16x8*)(qkv + qb + h * 64);
            #pragma unroll
            for (int p = 0; p < 2; ++p) {
                k8[hh][p] = *(const bf16x8*)(qkv + kb[p] + h * 64);
                v8[hh][p] = *(const bf16x8*)(qkv + kb[p] + h * 64 + 256);
            }
        }
        #pragma unroll
        for (int hh = 0; hh < 2; ++hh) {
            const u32x4 qw = __builtin_bit_cast(u32x4, q8[hh]);
            float sc[2];
            #pragma unroll
            for (int p = 0; p < 2; ++p) {
                const u32x4 kw = __builtin_bit_cast(u32x4, k8[hh][p]);
                float s = 0.f;
                #pragma unroll
                for (int w = 0; w < 4; ++w) s = dot2bf(qw[w], kw[w], s);
                s += __shfl_xor(s, 1, 64);
                s += __shfl_xor(s, 2, 64);
                s += __shfl_xor(s, 4, 64);
                sc[p] = valid[p] ? s * 0.125f : -1e30f;
            }
            const float p0 = __expf(sc[0]);
            const float p1 = __expf(sc[1]);
            float l = p0 + p1;
            l += __shfl_xor(l, 8, 64);
            l += __shfl_xor(l, 16, 64);
            l += __shfl_xor(l, 32, 64);

            // PV: pack (v0[j], v1[j]) via v_perm; dot2 against packed bf16 (p0, p1)
            const unsigned pp = (unsigned)(unsigned short)f2b(p0)
                              | ((unsigned)(unsigned short)f2b(p1) << 16);
            const u32x4 v0w = __builtin_bit_cast(u32x4, v8[hh][0]);
            const u32x4 v1w = __builtin_bit_cast(u32x4, v8[hh][1]);
            float o[8];
            #pragma unroll
            for (int j = 0; j < 8; ++j) {
                const unsigned pk = permb(v1w[j >> 1], v0w[j >> 1],
                                          (j & 1) ? 0x07060302u : 0x05040100u);
                o[j] = dot2bf(pk, pp, 0.f);
            }
            float r4[4];
            #pragma unroll
            for (int i = 0; i < 4; ++i) {
                const float a = o[2 * i], bb = o[2 * i + 1];
                const float mine = (n & 1) ? bb : a;
                const float theirs = (n & 1) ? a : bb;
                r4[i] = mine + __shfl_xor(theirs, 8, 64);
            }
            float r2[2];
            #pragma unroll
            for (int i = 0; i < 2; ++i) {
                const float a = r4[2 * i], bb = r4[2 * i + 1];
                const float mine = (n & 2) ? bb : a;
                const float theirs = (n & 2) ? a : bb;
                r2[i] = mine + __shfl_xor(theirs, 16, 64);
            }
            float ov;
            {
                const float a = r2[0], bb = r2[1];
                const float mine = (n & 4) ? bb : a;
                const float theirs = (n & 4) ? a : bb;
                ov = mine + __shfl_xor(theirs, 32, 64);
            }
            const float rl = __builtin_amdgcn_rcpf(l);
            ctx[ob + (hp * 2 + hh) * 64 + cg * 8 + n] = __float2bfloat16(ov * rl);
        }
    }
}

// ---------------- fused: ctx2 = ctx@out_w^T+out_b (in LDS), then proj+LN+ReLU+store ----------------
// r23 form (structural floor, 40.68us): 256 thr / 4 waves, per-wave acc[4][4], 72KB, 2 blk/CU.
__global__ __launch_bounds__(256, 2) void proj_ln_fused(const __hip_bfloat16* __restrict__ X,
                                                        const __hip_bfloat16* __restrict__ CTX,
                                                        const __hip_bfloat16* __restrict__ W2,
                                                        const float* __restrict__ out_b,
                                                        const __hip_bfloat16* __restrict__ W,
                                                        const float* __restrict__ bias,
                                                        const float* __restrict__ ln_g,
                                                        const float* __restrict__ ln_b,
                                                        float* __restrict__ out) {
    __shared__ __align__(16) short smem[36864];   // 72 KB
    __shared__ float mu_s[64], inv_s[64];
    short* c2s = smem;            // 64 x 256 (32 KB), persists through phase B
    short* As  = smem + 16384;    // 64 x 64 staging (8 KB)
    short* Bs  = smem + 20480;    // 256 x 64 staging (32 KB)
    const int tid = threadIdx.x;
    const int m0 = blockIdx.x * 64;
    const int b = m0 >> 12, sp0 = m0 & 4095;
    const int wave = tid >> 6, lane = tid & 63;
    const int wn = wave * 64;           // N-quarter; each wave spans all 64 M-rows
    const int fm = lane & 15;
    const int fq = lane >> 4;

    // ---- phase A: ctx2 tile ----
    {
        f32x4 acc2[4][4] = {};
        for (int k0 = 0; k0 < 256; k0 += 64) {
            #pragma unroll
            for (int v = 0; v < 2; ++v) {          // ctx: 512 chunks, 2 per thread
                const int q = v * 256 + tid;
                const int r = q >> 3;
                const int cs = (q & 7) ^ (r & 7);
                async_copy16(CTX + (size_t)(m0 + r) * 256 + k0 + cs * 8, &As[(v * 256 + wave * 64) * 8]);
            }
            #pragma unroll
            for (int v = 0; v < 8; ++v) {          // out_w: 2048 chunks, 8 per thread
                const int q = v * 256 + tid;
                const int r = q >> 3;
                const int cs = (q & 7) ^ (r & 7);
                async_copy16(W2 + (size_t)r * 256 + k0 + cs * 8, &Bs[(v * 256 + wave * 64) * 8]);
            }
            __syncthreads();
            #pragma unroll
            for (int kk = 0; kk < 2; ++kk) {
                bf16x8 af[4], bw[4];
                #pragma unroll
                for (int i = 0; i < 4; ++i) {
                    const int row = i * 16 + fm;
                    af[i] = *(const bf16x8*)(&As[row * 64 + (((fq + kk * 4) ^ (fm & 7)) * 8)]);
                }
                #pragma unroll
                for (int j = 0; j < 4; ++j) {
                    const int row = wn + j * 16 + fm;
                    bw[j] = *(const bf16x8*)(&Bs[row * 64 + (((fq + kk * 4) ^ (fm & 7)) * 8)]);
                }
                #pragma unroll
                for (int i = 0; i < 4; ++i)
                    #pragma unroll
                    for (int j = 0; j < 4; ++j)
                        acc2[i][j] = __builtin_amdgcn_mfma_f32_16x16x32_bf16(af[i], bw[j], acc2[i][j], 0, 0, 0);
            }
            __syncthreads();
        }
        #pragma unroll
        for (int j = 0; j < 4; ++j) {
            const int col = wn + j * 16 + fm;
            const float bv = out_b[col];
            const int jch = col >> 3, cl = col & 7;
            #pragma unroll
            for (int i = 0; i < 4; ++i)
                #pragma unroll
                for (int rr = 0; rr < 4; ++rr) {
                    const int row = i * 16 + fq * 4 + rr;
                    const int slot = (jch & 24) | ((jch & 7) ^ (row & 7));
                    c2s[row * 256 + slot * 8 + cl] = f2b(acc2[i][j][rr] + bv);
                }
        }
    }
    __syncthreads();

    // ---- phase B: proj GEMM over K=1024 groups [q | c2 | |q-c2| | q*c2] ----
    f32x4 acc[4][4] = {};
    for (int k0 = 0; k0 < 1024; k0 += 64) {
        const int g = k0 >> 8;
        const int cb = k0 & 255;
        #pragma unroll
        for (int v = 0; v < 8; ++v) {              // proj_w: 2048 chunks, 8 per thread
            const int q = v * 256 + tid;
            const int r = q >> 3;
            const int cs = (q & 7) ^ (r & 7);
            async_copy16(W + (size_t)r * 1024 + k0 + cs * 8, &Bs[(v * 256 + wave * 64) * 8]);
        }
        if (g == 0) {
            #pragma unroll
            for (int v = 0; v < 2; ++v) {
                const int q = v * 256 + tid;
                const int r = q >> 3;
                const int cs = (q & 7) ^ (r & 7);
                async_copy16(X + (size_t)(m0 + r) * 256 + cb + cs * 8, &As[(v * 256 + wave * 64) * 8]);
            }
        } else if (g >= 2) {
            #pragma unroll
            for (int v = 0; v < 2; ++v) {
                const int q = v * 256 + tid;
                const int r = q >> 3;
                const int cs = (q & 7) ^ (r & 7);
                int4 qraw = *(const int4*)(X + (size_t)(m0 + r) * 256 + cb + cs * 8);
                const int jch = (cb >> 3) + cs;
                const int slot = (jch & 24) | ((jch & 7) ^ (r & 7));
                int4 craw = *(const int4*)(&c2s[r * 256 + slot * 8]);
                const short* qs = (const short*)&qraw;
                const short* cw = (const short*)&craw;
                short tmp[8];
                #pragma unroll
                for (int j = 0; j < 8; ++j) {
                    const float qv = b2f(qs[j]), cv = b2f(cw[j]);
                    tmp[j] = f2b(g == 2 ? fabsf(qv - cv) : qv * cv);
                }
                *(int4*)(&As[q * 8]) = *(int4*)tmp;
            }
        }
        // g == 1: no A staging — frags read straight from c2s
        __syncthreads();
        #pragma unroll
        for (int kk = 0; kk < 2; ++kk) {
            bf16x8 af[4], bw[4];
            if (g == 1) {
                #pragma unroll
                for (int i = 0; i < 4; ++i) {
                    const int row = i * 16 + fm;
                    const int jch = (cb >> 3) + fq + kk * 4;
                    const int slot = (jch & 24) | ((jch & 7) ^ (row & 7));
                    af[i] = *(const bf16x8*)(&c2s[row * 256 + slot * 8]);
                }
            } else {
                #pragma unroll
                for (int i = 0; i < 4; ++i) {
                    const int row = i * 16 + fm;
                    af[i] = *(const bf16x8*)(&As[row * 64 + (((fq + kk * 4) ^ (fm & 7)) * 8)]);
                }
            }
            #pragma unroll
            for (int j = 0; j < 4; ++j) {
                const int row = wn + j * 16 + fm;
                bw[j] = *(const bf16x8*)(&Bs[row * 64 + (((fq + kk * 4) ^ (fm & 7)) * 8)]);
            }
            #pragma unroll
            for (int i = 0; i < 4; ++i)
                #pragma unroll
                for (int j = 0; j < 4; ++j)
                    acc[i][j] = __builtin_amdgcn_mfma_f32_16x16x32_bf16(af[i], bw[j], acc[i][j], 0, 0, 0);
        }
        __syncthreads();
    }
    // ---- epilogue: ys (bf16, stride 266) overlays c2s/As (dead); LN; ReLU; store ----
    short* ys = smem;
    #pragma unroll
    for (int j = 0; j < 4; ++j) {
        const int col = wn + j * 16 + fm;
        const float bv = bias[col];
        #pragma unroll
        for (int i = 0; i < 4; ++i)
            #pragma unroll
            for (int r = 0; r < 4; ++r)
                ys[(i * 16 + fq * 4 + r) * 266 + col] = f2b(acc[i][j][r] + bv);
    }
    __syncthreads();
    {
        const int tt = tid >> 2, seg = tid & 3;   // 64 rows x 4 segs of 64
        float s = 0.f, ss = 0.f;
        #pragma unroll
        for (int j = 0; j < 64; ++j) {
            const float v = b2f(ys[tt * 266 + seg * 64 + j]);
            s += v; ss += v * v;
        }
        s += __shfl_xor(s, 1, 64);  ss += __shfl_xor(ss, 1, 64);
        s += __shfl_xor(s, 2, 64);  ss += __shfl_xor(ss, 2, 64);
        if (seg == 0) {
            const float mu = s * (1.f / 256.f);
            const float var = ss * (1.f / 256.f) - mu * mu;
            mu_s[tt] = mu;
            inv_s[tt] = rsqrtf(var + 1e-5f);
        }
    }
    __syncthreads();
    {
        const int tl = tid & 63;                  // row 0..63
        const int j0 = tid >> 6;                  // 4 col-blocks of 64
        const float mu = mu_s[tl], inv = inv_s[tl];
        #pragma unroll
        for (int u = 0; u < 64; ++u) {
            const int j = j0 * 64 + u;
            const float v = (b2f(ys[tl * 266 + j]) - mu) * inv * ln_g[j] + ln_b[j];
            out[((size_t)(b * 256 + j) << 12) + sp0 + tl] = fmaxf(v, 0.f);
        }
    }
}

extern "C" void kernel_launch(void* const* d_in, const int* in_sizes, int n_in,
                              void* d_out, int out_size, void* d_ws, size_t ws_size,
                              hipStream_t stream) {
    (void)in_sizes; (void)n_in; (void)out_size; (void)ws_size;
    const float* feat   = (const float*)d_in[0];
    const float* in_w   = (const float*)d_in[1];
    const float* in_b   = (const float*)d_in[2];
    const float* out_w  = (const float*)d_in[3];
    const float* out_b  = (const float*)d_in[4];
    const float* proj_w = (const float*)d_in[5];
    const float* proj_b = (const float*)d_in[6];
    const float* ln_g   = (const float*)d_in[7];
    const float* ln_b   = (const float*)d_in[8];
    float* out = (float*)d_out;

    char* ws = (char*)d_ws;
    __hip_bfloat16* Xbf  = (__hip_bfloat16*)(ws);
    __hip_bfloat16* wbf  = (__hip_bfloat16*)(ws + (size_t)(16) * (1 << 20));
    __hip_bfloat16* qkv  = (__hip_bfloat16*)(ws + (size_t)(17) * (1 << 20));
    __hip_bfloat16* ctx  = (__hip_bfloat16*)(ws + (size_t)(65) * (1 << 20));
    __hip_bfloat16* in_wbf   = wbf;
    __hip_bfloat16* out_wbf  = wbf + 196608;
    __hip_bfloat16* proj_wbf = wbf + 262144;

    prep_kernel   <<<4352, 256, 0, stream>>>(feat, in_w, out_w, proj_w, Xbf, wbf);
    mfma_gemm<256, true><<<1536, 256, 0, stream>>>(Xbf, in_wbf, in_b, qkv, 768);
    attn_kernel   <<<NTOK / 4, 256, 0, stream>>>(qkv, ctx);
    proj_ln_fused <<<NTOK / 64, 256, 0, stream>>>(Xbf, ctx, out_wbf, out_b,
                                                  proj_wbf, proj_b, ln_g, ln_b, out);
}

// Round 13
// 176.418 us; speedup vs baseline: 1.1729x; 1.0167x over previous
//
#include <hip/hip_runtime.h>
#include <hip/hip_bf16.h>

// ContralateralAttention, round 25: r24 (best, 179.4) + XCD-chunked attn dispatch swizzle.
// attn grid 8192 % 8 == 0 -> bijective chunk swz=(bid&7)*1024+(bid>>3): each XCD processes
// exactly one batch image; K/V working set becomes a sliding ~500KB window (5 y-rows) that
// fits the 4MB per-XCD L2, vs round-robin where every L2 streams all 48MB of qkv.
// Everything else byte-identical to round 24 (proj 41.2 floor, dot2 attn, swizzled dbuf gemm).
// ws layout (MB): Xbf [0,16) | wbf [16,17) | qkv [17,65) | ctx [65,81)

#define NTOK 32768

using bf16x8 = __attribute__((ext_vector_type(8))) short;
using f32x4  = __attribute__((ext_vector_type(4))) float;
using u32x4  = __attribute__((ext_vector_type(4))) unsigned;

__device__ __forceinline__ float b2f(short s) {
    unsigned u = ((unsigned)(unsigned short)s) << 16;
    union { unsigned u; float f; } c; c.u = u; return c.f;
}
__device__ __forceinline__ short f2b(float f) {
    __hip_bfloat16 h = __float2bfloat16(f);
    return *(short*)&h;
}
__device__ __forceinline__ float dot2bf(unsigned a, unsigned b, float c) {
#if __has_builtin(__builtin_amdgcn_fdot2_f32_bf16)
    typedef __bf16 bf2 __attribute__((ext_vector_type(2)));
    return __builtin_amdgcn_fdot2_f32_bf16(__builtin_bit_cast(bf2, a),
                                           __builtin_bit_cast(bf2, b), c, false);
#else
    union { unsigned u; short s[2]; } ua, ub;
    ua.u = a; ub.u = b;
    return c + b2f(ua.s[0]) * b2f(ub.s[0]) + b2f(ua.s[1]) * b2f(ub.s[1]);
#endif
}
__device__ __forceinline__ unsigned permb(unsigned a, unsigned b, unsigned s) {
#if __has_builtin(__builtin_amdgcn_perm)
    return __builtin_amdgcn_perm(a, b, s);
#else
    unsigned long long v = ((unsigned long long)a << 32) | b;
    unsigned r = 0;
    #pragma unroll
    for (int i = 0; i < 4; ++i) r |= (unsigned)((v >> (((s >> (8 * i)) & 7) * 8)) & 0xff) << (8 * i);
    return r;
#endif
}
__device__ __forceinline__ void async_copy16(const void* g, void* l) {
    __builtin_amdgcn_global_load_lds(
        (const __attribute__((address_space(1))) unsigned int*)g,
        (__attribute__((address_space(3))) unsigned int*)l, 16, 0, 0);
}

// ---------------- prep: vectorized feat transpose+cast AND weight casts ----------------
__global__ __launch_bounds__(256) void prep_kernel(const float* __restrict__ feat,
                                                   const float* __restrict__ in_w,
                                                   const float* __restrict__ out_w,
                                                   const float* __restrict__ proj_w,
                                                   __hip_bfloat16* __restrict__ X,
                                                   __hip_bfloat16* __restrict__ wbf) {
    const int bid = blockIdx.x;
    const int tid = threadIdx.x;
    if (bid < 4096) {
        __shared__ float tile[32][68];
        const int b   = bid >> 9;
        const int rem = bid & 511;
        const int sp0 = (rem & 63) * 64;
        const int c0  = (rem >> 6) * 32;
        #pragma unroll
        for (int u = 0; u < 2; ++u) {
            const int idx = tid + u * 256;      // 0..511
            const int cl = idx >> 4;            // 0..31
            const int sq = (idx & 15) * 4;      // 0..60
            const float4 v = *(const float4*)(feat + ((size_t)(b * 256 + c0 + cl) << 12) + sp0 + sq);
            tile[cl][sq]     = v.x;
            tile[cl][sq + 1] = v.y;
            tile[cl][sq + 2] = v.z;
            tile[cl][sq + 3] = v.w;
        }
        __syncthreads();
        #pragma unroll
        for (int u = 0; u < 2; ++u) {
            const int idx = tid + u * 256;      // 0..511
            const int tok = idx >> 3;           // 0..63
            const int cq  = (idx & 7) * 4;      // 0..28
            short4 s;
            s.x = f2b(tile[cq][tok]);
            s.y = f2b(tile[cq + 1][tok]);
            s.z = f2b(tile[cq + 2][tok]);
            s.w = f2b(tile[cq + 3][tok]);
            *(short4*)(X + (size_t)(b * 4096 + sp0 + tok) * 256 + c0 + cq) = s;
        }
    } else {
        const int i4 = (bid - 4096) * 1024 + tid * 4;
        if (i4 < 196608) {
            const float4 v = *(const float4*)(in_w + i4);
            short4 s = {f2b(v.x), f2b(v.y), f2b(v.z), f2b(v.w)};
            *(short4*)(wbf + i4) = s;
        }
        if (i4 < 65536) {
            const float4 v = *(const float4*)(out_w + i4);
            short4 s = {f2b(v.x), f2b(v.y), f2b(v.z), f2b(v.w)};
            *(short4*)(wbf + 196608 + i4) = s;
        }
        if (i4 < 262144) {
            const float4 v = *(const float4*)(proj_w + i4);
            short4 s = {f2b(v.x), f2b(v.y), f2b(v.z), f2b(v.w)};
            *(short4*)(wbf + 262144 + i4) = s;
        }
    }
}

// ---------------- MFMA GEMM (qkv): 256 thr, M=128 x N=128, BK=64, 2-phase dbuf ----------------
// 1D grid 1536, XCD-chunked work order: work=(bid&7)*192+(bid>>3); xb=work/6 (A-tile), yb=work%6.
template <int KDIM, bool OUT_BF16>
__global__ __launch_bounds__(256) void mfma_gemm(const __hip_bfloat16* __restrict__ A,
                                                 const __hip_bfloat16* __restrict__ W,
                                                 const float* __restrict__ bias,
                                                 void* __restrict__ C, int Ntot) {
    __shared__ __align__(16) short As[2][128 * 64];   // 2 x 16 KB
    __shared__ __align__(16) short Bs[2][128 * 64];   // 2 x 16 KB
    const int tid = threadIdx.x;
    const int work = (blockIdx.x & 7) * 192 + (blockIdx.x >> 3);
    const int m0 = (work / 6) * 128;
    const int n0 = (work % 6) * 128;
    const int wave = tid >> 6, lane = tid & 63;
    const int wm = (wave >> 1) * 64;
    const int wn = (wave & 1) * 64;
    const int fm = lane & 15;
    const int fq = lane >> 4;

    // prologue: stage K-slice 0 into buffer 0
    #pragma unroll
    for (int v = 0; v < 4; ++v) {
        const int qb = v * 256 + wave * 64;
        const int q = qb + lane;
        const int r = q >> 3;
        const int cs = (q & 7) ^ (r & 7);
        async_copy16(A + (size_t)(m0 + r) * KDIM + cs * 8, &As[0][qb * 8]);
        async_copy16(W + (size_t)(n0 + r) * KDIM + cs * 8, &Bs[0][qb * 8]);
    }
    __syncthreads();

    f32x4 acc[4][4] = {};
    #pragma unroll
    for (int t = 0; t < KDIM / 64; ++t) {
        const int cur = t & 1;
        if (t + 1 < KDIM / 64) {                       // issue next-slice stage FIRST
            #pragma unroll
            for (int v = 0; v < 4; ++v) {
                const int qb = v * 256 + wave * 64;
                const int q = qb + lane;
                const int r = q >> 3;
                const int cs = (q & 7) ^ (r & 7);
                async_copy16(A + (size_t)(m0 + r) * KDIM + (t + 1) * 64 + cs * 8, &As[cur ^ 1][qb * 8]);
                async_copy16(W + (size_t)(n0 + r) * KDIM + (t + 1) * 64 + cs * 8, &Bs[cur ^ 1][qb * 8]);
            }
        }
        #pragma unroll
        for (int kk = 0; kk < 2; ++kk) {
            bf16x8 af[4], bw[4];
            #pragma unroll
            for (int i = 0; i < 4; ++i) {
                const int row = wm + i * 16 + fm;
                af[i] = *(const bf16x8*)(&As[cur][row * 64 + (((fq + kk * 4) ^ (fm & 7)) * 8)]);
            }
            #pragma unroll
            for (int j = 0; j < 4; ++j) {
                const int row = wn + j * 16 + fm;
                bw[j] = *(const bf16x8*)(&Bs[cur][row * 64 + (((fq + kk * 4) ^ (fm & 7)) * 8)]);
            }
            #pragma unroll
            for (int i = 0; i < 4; ++i)
                #pragma unroll
                for (int j = 0; j < 4; ++j)
                    acc[i][j] = __builtin_amdgcn_mfma_f32_16x16x32_bf16(af[i], bw[j], acc[i][j], 0, 0, 0);
        }
        __syncthreads();                               // one barrier per K-step
    }
    #pragma unroll
    for (int j = 0; j < 4; ++j) {
        const int col = n0 + wn + j * 16 + fm;
        const float bv = bias[col];
        #pragma unroll
        for (int i = 0; i < 4; ++i) {
            #pragma unroll
            for (int r = 0; r < 4; ++r) {
                const int row = m0 + wm + i * 16 + fq * 4 + r;
                const float v = acc[i][j][r] + bv;
                if (OUT_BF16)
                    ((__hip_bfloat16*)C)[(size_t)row * Ntot + col] = __float2bfloat16(v);
                else
                    ((float*)C)[(size_t)row * Ntot + col] = v;
            }
        }
    }
}

// ---------------- sparse attention (r7 dataflow; dot2/perm inner math; XCD-chunked) ----------------
#define P0DY ((2u)|(2u<<3)|(2u<<6)|(2u<<9)|(2u<<12)|(1u<<15)|(1u<<18)|(1u<<21))
#define P0DX ((2u)|(1u<<3)|(3u<<6)|(0u<<9)|(4u<<12)|(2u<<15)|(1u<<18)|(3u<<21))
#define P1DY ((3u)|(3u<<3)|(3u<<6)|(0u<<9)|(4u<<12)|(2u<<15)|(2u<<18)|(2u<<21))
#define P1DX ((2u)|(1u<<3)|(3u<<6)|(2u<<9)|(2u<<12)|(2u<<15)|(2u<<18)|(2u<<21))

__global__ __launch_bounds__(256) void attn_kernel(const __hip_bfloat16* __restrict__ qkv,
                                                   __hip_bfloat16* __restrict__ ctx) {
    // XCD-chunked bijective swizzle (8192 blocks % 8 == 0): each XCD owns one batch image,
    // so its L2 working set is a sliding ~500KB window of K/V rows instead of all 48MB.
    const int swz = (blockIdx.x & 7) * 1024 + (blockIdx.x >> 3);
    const int t = swz * 4 + (threadIdx.x >> 6);
    const int lane = threadIdx.x & 63;
    const int n  = lane >> 3;
    const int cg = lane & 7;
    const int x6 = t & 63;
    const int yq = (t >> 6) & 63;
    const int b  = t >> 12;
    const int side = x6 >> 5;
    const int x = x6 & 31;

    bool valid[2];
    size_t kb[2];
    #pragma unroll
    for (int p = 0; p < 2; ++p) {
        const unsigned dyp = p ? P1DY : P0DY;
        const unsigned dxp = p ? P1DX : P0DX;
        const int sh = 3 * n;
        const int dy = (int)((dyp >> sh) & 7) - 2;
        const int dx = (int)((dxp >> sh) & 7) - 2;
        const int yy = yq + dy, xx = x + dx;
        valid[p] = (p == 0 || n < 5) && yy >= 0 && yy < 64 && xx >= 0 && xx < 32;
        const int xm = side ? (31 - xx) : (63 - xx);
        int tm = (b << 12) + (yy << 6) + xm;
        if (!valid[p]) tm = t;
        kb[p] = (size_t)tm * 768 + 256 + cg * 8;
    }
    const size_t qb = (size_t)t * 768 + cg * 8;
    const size_t ob = (size_t)t * 256;

    #pragma unroll
    for (int hp = 0; hp < 2; ++hp) {
        bf16x8 q8[2], k8[2][2], v8[2][2];
        #pragma unroll
        for (int hh = 0; hh < 2; ++hh) {
            const int h = hp * 2 + hh;
            q8[hh] = *(const bf16x8*)(qkv + qb + h * 64);
            #pragma unroll
            for (int p = 0; p < 2; ++p) {
                k8[hh][p] = *(const bf16x8*)(qkv + kb[p] + h * 64);
                v8[hh][p] = *(const bf16x8*)(qkv + kb[p] + h * 64 + 256);
            }
        }
        #pragma unroll
        for (int hh = 0; hh < 2; ++hh) {
            const u32x4 qw = __builtin_bit_cast(u32x4, q8[hh]);
            float sc[2];
            #pragma unroll
            for (int p = 0; p < 2; ++p) {
                const u32x4 kw = __builtin_bit_cast(u32x4, k8[hh][p]);
                float s = 0.f;
                #pragma unroll
                for (int w = 0; w < 4; ++w) s = dot2bf(qw[w], kw[w], s);
                s += __shfl_xor(s, 1, 64);
                s += __shfl_xor(s, 2, 64);
                s += __shfl_xor(s, 4, 64);
                sc[p] = valid[p] ? s * 0.125f : -1e30f;
            }
            const float p0 = __expf(sc[0]);
            const float p1 = __expf(sc[1]);
            float l = p0 + p1;
            l += __shfl_xor(l, 8, 64);
            l += __shfl_xor(l, 16, 64);
            l += __shfl_xor(l, 32, 64);

            // PV: pack (v0[j], v1[j]) via v_perm; dot2 against packed bf16 (p0, p1)
            const unsigned pp = (unsigned)(unsigned short)f2b(p0)
                              | ((unsigned)(unsigned short)f2b(p1) << 16);
            const u32x4 v0w = __builtin_bit_cast(u32x4, v8[hh][0]);
            const u32x4 v1w = __builtin_bit_cast(u32x4, v8[hh][1]);
            float o[8];
            #pragma unroll
            for (int j = 0; j < 8; ++j) {
                const unsigned pk = permb(v1w[j >> 1], v0w[j >> 1],
                                          (j & 1) ? 0x07060302u : 0x05040100u);
                o[j] = dot2bf(pk, pp, 0.f);
            }
            float r4[4];
            #pragma unroll
            for (int i = 0; i < 4; ++i) {
                const float a = o[2 * i], bb = o[2 * i + 1];
                const float mine = (n & 1) ? bb : a;
                const float theirs = (n & 1) ? a : bb;
                r4[i] = mine + __shfl_xor(theirs, 8, 64);
            }
            float r2[2];
            #pragma unroll
            for (int i = 0; i < 2; ++i) {
                const float a = r4[2 * i], bb = r4[2 * i + 1];
                const float mine = (n & 2) ? bb : a;
                const float theirs = (n & 2) ? a : bb;
                r2[i] = mine + __shfl_xor(theirs, 16, 64);
            }
            float ov;
            {
                const float a = r2[0], bb = r2[1];
                const float mine = (n & 4) ? bb : a;
                const float theirs = (n & 4) ? a : bb;
                ov = mine + __shfl_xor(theirs, 32, 64);
            }
            const float rl = __builtin_amdgcn_rcpf(l);
            ctx[ob + (hp * 2 + hh) * 64 + cg * 8 + n] = __float2bfloat16(ov * rl);
        }
    }
}

// ---------------- fused: ctx2 = ctx@out_w^T+out_b (in LDS), then proj+LN+ReLU+store ----------------
// r23 form (structural floor, ~41us): 256 thr / 4 waves, per-wave acc[4][4], 72KB, 2 blk/CU.
__global__ __launch_bounds__(256, 2) void proj_ln_fused(const __hip_bfloat16* __restrict__ X,
                                                        const __hip_bfloat16* __restrict__ CTX,
                                                        const __hip_bfloat16* __restrict__ W2,
                                                        const float* __restrict__ out_b,
                                                        const __hip_bfloat16* __restrict__ W,
                                                        const float* __restrict__ bias,
                                                        const float* __restrict__ ln_g,
                                                        const float* __restrict__ ln_b,
                                                        float* __restrict__ out) {
    __shared__ __align__(16) short smem[36864];   // 72 KB
    __shared__ float mu_s[64], inv_s[64];
    short* c2s = smem;            // 64 x 256 (32 KB), persists through phase B
    short* As  = smem + 16384;    // 64 x 64 staging (8 KB)
    short* Bs  = smem + 20480;    // 256 x 64 staging (32 KB)
    const int tid = threadIdx.x;
    const int m0 = blockIdx.x * 64;
    const int b = m0 >> 12, sp0 = m0 & 4095;
    const int wave = tid >> 6, lane = tid & 63;
    const int wn = wave * 64;           // N-quarter; each wave spans all 64 M-rows
    const int fm = lane & 15;
    const int fq = lane >> 4;

    // ---- phase A: ctx2 tile ----
    {
        f32x4 acc2[4][4] = {};
        for (int k0 = 0; k0 < 256; k0 += 64) {
            #pragma unroll
            for (int v = 0; v < 2; ++v) {          // ctx: 512 chunks, 2 per thread
                const int q = v * 256 + tid;
                const int r = q >> 3;
                const int cs = (q & 7) ^ (r & 7);
                async_copy16(CTX + (size_t)(m0 + r) * 256 + k0 + cs * 8, &As[(v * 256 + wave * 64) * 8]);
            }
            #pragma unroll
            for (int v = 0; v < 8; ++v) {          // out_w: 2048 chunks, 8 per thread
                const int q = v * 256 + tid;
                const int r = q >> 3;
                const int cs = (q & 7) ^ (r & 7);
                async_copy16(W2 + (size_t)r * 256 + k0 + cs * 8, &Bs[(v * 256 + wave * 64) * 8]);
            }
            __syncthreads();
            #pragma unroll
            for (int kk = 0; kk < 2; ++kk) {
                bf16x8 af[4], bw[4];
                #pragma unroll
                for (int i = 0; i < 4; ++i) {
                    const int row = i * 16 + fm;
                    af[i] = *(const bf16x8*)(&As[row * 64 + (((fq + kk * 4) ^ (fm & 7)) * 8)]);
                }
                #pragma unroll
                for (int j = 0; j < 4; ++j) {
                    const int row = wn + j * 16 + fm;
                    bw[j] = *(const bf16x8*)(&Bs[row * 64 + (((fq + kk * 4) ^ (fm & 7)) * 8)]);
                }
                #pragma unroll
                for (int i = 0; i < 4; ++i)
                    #pragma unroll
                    for (int j = 0; j < 4; ++j)
                        acc2[i][j] = __builtin_amdgcn_mfma_f32_16x16x32_bf16(af[i], bw[j], acc2[i][j], 0, 0, 0);
            }
            __syncthreads();
        }
        #pragma unroll
        for (int j = 0; j < 4; ++j) {
            const int col = wn + j * 16 + fm;
            const float bv = out_b[col];
            const int jch = col >> 3, cl = col & 7;
            #pragma unroll
            for (int i = 0; i < 4; ++i)
                #pragma unroll
                for (int rr = 0; rr < 4; ++rr) {
                    const int row = i * 16 + fq * 4 + rr;
                    const int slot = (jch & 24) | ((jch & 7) ^ (row & 7));
                    c2s[row * 256 + slot * 8 + cl] = f2b(acc2[i][j][rr] + bv);
                }
        }
    }
    __syncthreads();

    // ---- phase B: proj GEMM over K=1024 groups [q | c2 | |q-c2| | q*c2] ----
    f32x4 acc[4][4] = {};
    for (int k0 = 0; k0 < 1024; k0 += 64) {
        const int g = k0 >> 8;
        const int cb = k0 & 255;
        #pragma unroll
        for (int v = 0; v < 8; ++v) {              // proj_w: 2048 chunks, 8 per thread
            const int q = v * 256 + tid;
            const int r = q >> 3;
            const int cs = (q & 7) ^ (r & 7);
            async_copy16(W + (size_t)r * 1024 + k0 + cs * 8, &Bs[(v * 256 + wave * 64) * 8]);
        }
        if (g == 0) {
            #pragma unroll
            for (int v = 0; v < 2; ++v) {
                const int q = v * 256 + tid;
                const int r = q >> 3;
                const int cs = (q & 7) ^ (r & 7);
                async_copy16(X + (size_t)(m0 + r) * 256 + cb + cs * 8, &As[(v * 256 + wave * 64) * 8]);
            }
        } else if (g >= 2) {
            #pragma unroll
            for (int v = 0; v < 2; ++v) {
                const int q = v * 256 + tid;
                const int r = q >> 3;
                const int cs = (q & 7) ^ (r & 7);
                int4 qraw = *(const int4*)(X + (size_t)(m0 + r) * 256 + cb + cs * 8);
                const int jch = (cb >> 3) + cs;
                const int slot = (jch & 24) | ((jch & 7) ^ (r & 7));
                int4 craw = *(const int4*)(&c2s[r * 256 + slot * 8]);
                const short* qs = (const short*)&qraw;
                const short* cw = (const short*)&craw;
                short tmp[8];
                #pragma unroll
                for (int j = 0; j < 8; ++j) {
                    const float qv = b2f(qs[j]), cv = b2f(cw[j]);
                    tmp[j] = f2b(g == 2 ? fabsf(qv - cv) : qv * cv);
                }
                *(int4*)(&As[q * 8]) = *(int4*)tmp;
            }
        }
        // g == 1: no A staging — frags read straight from c2s
        __syncthreads();
        #pragma unroll
        for (int kk = 0; kk < 2; ++kk) {
            bf16x8 af[4], bw[4];
            if (g == 1) {
                #pragma unroll
                for (int i = 0; i < 4; ++i) {
                    const int row = i * 16 + fm;
                    const int jch = (cb >> 3) + fq + kk * 4;
                    const int slot = (jch & 24) | ((jch & 7) ^ (row & 7));
                    af[i] = *(const bf16x8*)(&c2s[row * 256 + slot * 8]);
                }
            } else {
                #pragma unroll
                for (int i = 0; i < 4; ++i) {
                    const int row = i * 16 + fm;
                    af[i] = *(const bf16x8*)(&As[row * 64 + (((fq + kk * 4) ^ (fm & 7)) * 8)]);
                }
            }
            #pragma unroll
            for (int j = 0; j < 4; ++j) {
                const int row = wn + j * 16 + fm;
                bw[j] = *(const bf16x8*)(&Bs[row * 64 + (((fq + kk * 4) ^ (fm & 7)) * 8)]);
            }
            #pragma unroll
            for (int i = 0; i < 4; ++i)
                #pragma unroll
                for (int j = 0; j < 4; ++j)
                    acc[i][j] = __builtin_amdgcn_mfma_f32_16x16x32_bf16(af[i], bw[j], acc[i][j], 0, 0, 0);
        }
        __syncthreads();
    }
    // ---- epilogue: ys (bf16, stride 266) overlays c2s/As (dead); LN; ReLU; store ----
    short* ys = smem;
    #pragma unroll
    for (int j = 0; j < 4; ++j) {
        const int col = wn + j * 16 + fm;
        const float bv = bias[col];
        #pragma unroll
        for (int i = 0; i < 4; ++i)
            #pragma unroll
            for (int r = 0; r < 4; ++r)
                ys[(i * 16 + fq * 4 + r) * 266 + col] = f2b(acc[i][j][r] + bv);
    }
    __syncthreads();
    {
        const int tt = tid >> 2, seg = tid & 3;   // 64 rows x 4 segs of 64
        float s = 0.f, ss = 0.f;
        #pragma unroll
        for (int j = 0; j < 64; ++j) {
            const float v = b2f(ys[tt * 266 + seg * 64 + j]);
            s += v; ss += v * v;
        }
        s += __shfl_xor(s, 1, 64);  ss += __shfl_xor(ss, 1, 64);
        s += __shfl_xor(s, 2, 64);  ss += __shfl_xor(ss, 2, 64);
        if (seg == 0) {
            const float mu = s * (1.f / 256.f);
            const float var = ss * (1.f / 256.f) - mu * mu;
            mu_s[tt] = mu;
            inv_s[tt] = rsqrtf(var + 1e-5f);
        }
    }
    __syncthreads();
    {
        const int tl = tid & 63;                  // row 0..63
        const int j0 = tid >> 6;                  // 4 col-blocks of 64
        const float mu = mu_s[tl], inv = inv_s[tl];
        #pragma unroll
        for (int u = 0; u < 64; ++u) {
            const int j = j0 * 64 + u;
            const float v = (b2f(ys[tl * 266 + j]) - mu) * inv * ln_g[j] + ln_b[j];
            out[((size_t)(b * 256 + j) << 12) + sp0 + tl] = fmaxf(v, 0.f);
        }
    }
}

extern "C" void kernel_launch(void* const* d_in, const int* in_sizes, int n_in,
                              void* d_out, int out_size, void* d_ws, size_t ws_size,
                              hipStream_t stream) {
    (void)in_sizes; (void)n_in; (void)out_size; (void)ws_size;
    const float* feat   = (const float*)d_in[0];
    const float* in_w   = (const float*)d_in[1];
    const float* in_b   = (const float*)d_in[2];
    const float* out_w  = (const float*)d_in[3];
    const float* out_b  = (const float*)d_in[4];
    const float* proj_w = (const float*)d_in[5];
    const float* proj_b = (const float*)d_in[6];
    const float* ln_g   = (const float*)d_in[7];
    const float* ln_b   = (const float*)d_in[8];
    float* out = (float*)d_out;

    char* ws = (char*)d_ws;
    __hip_bfloat16* Xbf  = (__hip_bfloat16*)(ws);
    __hip_bfloat16* wbf  = (__hip_bfloat16*)(ws + (size_t)(16) * (1 << 20));
    __hip_bfloat16* qkv  = (__hip_bfloat16*)(ws + (size_t)(17) * (1 << 20));
    __hip_bfloat16* ctx  = (__hip_bfloat16*)(ws + (size_t)(65) * (1 << 20));
    __hip_bfloat16* in_wbf   = wbf;
    __hip_bfloat16* out_wbf  = wbf + 196608;
    __hip_bfloat16* proj_wbf = wbf + 262144;

    prep_kernel   <<<4352, 256, 0, stream>>>(feat, in_w, out_w, proj_w, Xbf, wbf);
    mfma_gemm<256, true><<<1536, 256, 0, stream>>>(Xbf, in_wbf, in_b, qkv, 768);
    attn_kernel   <<<NTOK / 4, 256, 0, stream>>>(qkv, ctx);
    proj_ln_fused <<<NTOK / 64, 256, 0, stream>>>(Xbf, ctx, out_wbf, out_b,
                                                  proj_wbf, proj_b, ln_g, ln_b, out);
}